// Round 1
// baseline (293.481 us; speedup 1.0000x reference)
//
#include <hip/hip_runtime.h>
#include <math.h>

#define IN_DIM 128
#define NH 4
#define DD 32
#define EDIM 32
#define NEG_SLOPE 0.2f

// ---------------------------------------------------------------------------
// h_e_t[t,h] = sum_k a_e[h,k] * (sum_e edge_emb[t,e] * W_r[t,e,h*32+k])
// One block of T*128 threads.
__global__ void k_edge_type(const float* __restrict__ edge_emb,
                            const float* __restrict__ W_r,
                            const float* __restrict__ a_e,
                            float* __restrict__ h_e_t)
{
    int tid = threadIdx.x;
    int t = tid >> 7;          // edge type
    int rem = tid & 127;       // f = h*32+k
    int k = rem & 31;
    int h = rem >> 5;
    float v = 0.f;
#pragma unroll
    for (int e = 0; e < EDIM; ++e)
        v += edge_emb[t * EDIM + e] * W_r[(size_t)(t * EDIM + e) * 128 + rem];
    v *= a_e[rem];
#pragma unroll
    for (int off = 16; off >= 1; off >>= 1)
        v += __shfl_xor(v, off);
    if (k == 0) h_e_t[t * NH + h] = v;
}

// ---------------------------------------------------------------------------
// C = A @ B (+bias).  A: [M][128] f32.  B: [128][128].  Tile 128x128, 8x8/thread.
// blockIdx.y == 0 -> W -> emb ; blockIdx.y == 1 -> res_w (+res_b) -> res
__global__ __launch_bounds__(256) void k_gemm(
    const float* __restrict__ A, const float* __restrict__ W,
    const float* __restrict__ Rw, const float* __restrict__ Rb,
    float* __restrict__ Emb, float* __restrict__ Res, int M)
{
    const float* B = (blockIdx.y == 0) ? W : Rw;
    float* C = (blockIdx.y == 0) ? Emb : Res;
    __shared__ float As[16][128];   // [k][m]
    __shared__ float Bs[16][128];   // [k][n]
    int tid = threadIdx.x;
    int tx = tid & 15, ty = tid >> 4;
    int m0 = blockIdx.x * 128;
    float acc[8][8];
#pragma unroll
    for (int i = 0; i < 8; ++i)
#pragma unroll
        for (int j = 0; j < 8; ++j) acc[i][j] = 0.f;

    for (int k0 = 0; k0 < 128; k0 += 16) {
#pragma unroll
        for (int i = 0; i < 2; ++i) {
            int idx = tid * 2 + i;            // 0..511
            int ar = idx >> 2, ac = (idx & 3) << 2;
            float4 v = make_float4(0.f, 0.f, 0.f, 0.f);
            if (m0 + ar < M) v = *(const float4*)&A[(size_t)(m0 + ar) * 128 + k0 + ac];
            As[ac + 0][ar] = v.x; As[ac + 1][ar] = v.y;
            As[ac + 2][ar] = v.z; As[ac + 3][ar] = v.w;
            int br = idx >> 5, bc = (idx & 31) << 2;
            *(float4*)&Bs[br][bc] = *(const float4*)&B[(size_t)(k0 + br) * 128 + bc];
        }
        __syncthreads();
#pragma unroll
        for (int k = 0; k < 16; ++k) {
            float a[8], b[8];
            *(float4*)&a[0] = *(const float4*)&As[k][ty * 8];
            *(float4*)&a[4] = *(const float4*)&As[k][ty * 8 + 4];
            *(float4*)&b[0] = *(const float4*)&Bs[k][tx * 8];
            *(float4*)&b[4] = *(const float4*)&Bs[k][tx * 8 + 4];
#pragma unroll
            for (int i = 0; i < 8; ++i)
#pragma unroll
                for (int j = 0; j < 8; ++j) acc[i][j] += a[i] * b[j];
        }
        __syncthreads();
    }
    bool bias = (blockIdx.y == 1);
#pragma unroll
    for (int i = 0; i < 8; ++i) {
        int r = m0 + ty * 8 + i;
        if (r < M) {
            float4 o0, o1;
            o0.x = acc[i][0] + (bias ? Rb[tx * 8 + 0] : 0.f);
            o0.y = acc[i][1] + (bias ? Rb[tx * 8 + 1] : 0.f);
            o0.z = acc[i][2] + (bias ? Rb[tx * 8 + 2] : 0.f);
            o0.w = acc[i][3] + (bias ? Rb[tx * 8 + 3] : 0.f);
            o1.x = acc[i][4] + (bias ? Rb[tx * 8 + 4] : 0.f);
            o1.y = acc[i][5] + (bias ? Rb[tx * 8 + 5] : 0.f);
            o1.z = acc[i][6] + (bias ? Rb[tx * 8 + 6] : 0.f);
            o1.w = acc[i][7] + (bias ? Rb[tx * 8 + 7] : 0.f);
            *(float4*)&C[(size_t)r * 128 + tx * 8] = o0;
            *(float4*)&C[(size_t)r * 128 + tx * 8 + 4] = o1;
        }
    }
}

// ---------------------------------------------------------------------------
// h_l[n,h] = sum_d a_l[h,d]*emb[n,h,d];  h_r likewise.  One wave per node.
__global__ __launch_bounds__(256) void k_rowdots(
    const float* __restrict__ emb, const float* __restrict__ a_l,
    const float* __restrict__ a_r, float* __restrict__ h_l,
    float* __restrict__ h_r, int N)
{
    int n = (blockIdx.x * blockDim.x + threadIdx.x) >> 6;
    if (n >= N) return;
    int lane = threadIdx.x & 63;
    float2 e  = *(const float2*)&emb[(size_t)n * 128 + lane * 2];
    float2 al = *(const float2*)&a_l[lane * 2];
    float2 ar = *(const float2*)&a_r[lane * 2];
    float vl = e.x * al.x + e.y * al.y;
    float vr = e.x * ar.x + e.y * ar.y;
#pragma unroll
    for (int off = 8; off >= 1; off >>= 1) {
        vl += __shfl_xor(vl, off);
        vr += __shfl_xor(vr, off);
    }
    if ((lane & 15) == 0) {
        int h = lane >> 4;
        h_l[(size_t)n * 4 + h] = vl;
        h_r[(size_t)n * 4 + h] = vr;
    }
}

// ---------------------------------------------------------------------------
__global__ void k_zero(int* p, int n) {
    int i = blockIdx.x * blockDim.x + threadIdx.x;
    if (i < n) p[i] = 0;
}

__global__ void k_hist(const int* __restrict__ col, int* __restrict__ cnt, int E) {
    int i = blockIdx.x * blockDim.x + threadIdx.x;
    if (i < E) atomicAdd(&cnt[col[i]], 1);
}

__global__ void k_scan1(const int* __restrict__ cnt, int* __restrict__ starts,
                        int* __restrict__ bsum, int N)
{
    __shared__ int sh[256];
    int t = threadIdx.x, n = blockIdx.x * 256 + t;
    int v = (n < N) ? cnt[n] : 0;
    sh[t] = v; __syncthreads();
    for (int off = 1; off < 256; off <<= 1) {
        int y = (t >= off) ? sh[t - off] : 0;
        __syncthreads();
        sh[t] += y;
        __syncthreads();
    }
    if (n < N) starts[n] = sh[t] - v;
    if (t == 255) bsum[blockIdx.x] = sh[255];
}

__global__ void k_scan2(const int* __restrict__ bsum, int* __restrict__ boff, int nb)
{
    __shared__ int sh[256];
    int t = threadIdx.x;
    int v = (t < nb) ? bsum[t] : 0;
    sh[t] = v; __syncthreads();
    for (int off = 1; off < 256; off <<= 1) {
        int y = (t >= off) ? sh[t - off] : 0;
        __syncthreads();
        sh[t] += y;
        __syncthreads();
    }
    if (t < nb) boff[t] = sh[t] - v;
}

__global__ void k_scan3(int* __restrict__ starts, const int* __restrict__ boff,
                        int* __restrict__ cursor, int N, int E)
{
    int t = threadIdx.x, n = blockIdx.x * 256 + t;
    if (n < N) {
        int st = starts[n] + boff[blockIdx.x];
        starts[n] = st;
        cursor[n] = st;
    }
    if (n == 0) starts[N] = E;
}

__global__ void k_fill(const int* __restrict__ col, int* __restrict__ cursor,
                       int* __restrict__ eidx, int E)
{
    int i = blockIdx.x * blockDim.x + threadIdx.x;
    if (i < E) {
        int pos = atomicAdd(&cursor[col[i]], 1);
        eidx[pos] = i;
    }
}

// ---------------------------------------------------------------------------
// One wave per destination node: local softmax over its incoming edges, then
// agg = sum alpha * emb[row], fused with residual + transpose + ELU epilogue.
__global__ __launch_bounds__(256) void k_aggregate(
    const int* __restrict__ eidx, const int* __restrict__ starts,
    const int* __restrict__ row, const int* __restrict__ etype,
    const float* __restrict__ h_l, const float* __restrict__ h_r,
    const float* __restrict__ h_e_t, const float* __restrict__ emb,
    const float* __restrict__ res, float* __restrict__ out, int N)
{
    int n = (blockIdx.x * blockDim.x + threadIdx.x) >> 6;
    if (n >= N) return;
    int lane = threadIdx.x & 63;
    int st0 = starts[n];
    int deg = starts[n + 1] - st0;
    float4 hrv = *(const float4*)&h_r[(size_t)n * 4];

    // ---- pass 1: max per head ----
    float m0 = -INFINITY, m1 = -INFINITY, m2 = -INFINITY, m3 = -INFINITY;
    for (int base = 0; base < deg; base += 64) {
        int el = base + lane;
        float sc0 = -INFINITY, sc1 = -INFINITY, sc2 = -INFINITY, sc3 = -INFINITY;
        if (el < deg) {
            int e = eidx[st0 + el];
            float4 hl = *(const float4*)&h_l[(size_t)row[e] * 4];
            float4 he = *(const float4*)&h_e_t[(size_t)etype[e] * 4];
            sc0 = hl.x + hrv.x + he.x; sc0 = sc0 > 0.f ? sc0 : NEG_SLOPE * sc0;
            sc1 = hl.y + hrv.y + he.y; sc1 = sc1 > 0.f ? sc1 : NEG_SLOPE * sc1;
            sc2 = hl.z + hrv.z + he.z; sc2 = sc2 > 0.f ? sc2 : NEG_SLOPE * sc2;
            sc3 = hl.w + hrv.w + he.w; sc3 = sc3 > 0.f ? sc3 : NEG_SLOPE * sc3;
        }
#pragma unroll
        for (int off = 32; off >= 1; off >>= 1) {
            sc0 = fmaxf(sc0, __shfl_xor(sc0, off));
            sc1 = fmaxf(sc1, __shfl_xor(sc1, off));
            sc2 = fmaxf(sc2, __shfl_xor(sc2, off));
            sc3 = fmaxf(sc3, __shfl_xor(sc3, off));
        }
        m0 = fmaxf(m0, sc0); m1 = fmaxf(m1, sc1);
        m2 = fmaxf(m2, sc2); m3 = fmaxf(m3, sc3);
    }

    // ---- pass 2: softmax denominator per head ----
    float d0 = 0.f, d1 = 0.f, d2 = 0.f, d3 = 0.f;
    for (int base = 0; base < deg; base += 64) {
        int el = base + lane;
        float p0 = 0.f, p1 = 0.f, p2 = 0.f, p3 = 0.f;
        if (el < deg) {
            int e = eidx[st0 + el];
            float4 hl = *(const float4*)&h_l[(size_t)row[e] * 4];
            float4 he = *(const float4*)&h_e_t[(size_t)etype[e] * 4];
            float sc0 = hl.x + hrv.x + he.x; sc0 = sc0 > 0.f ? sc0 : NEG_SLOPE * sc0;
            float sc1 = hl.y + hrv.y + he.y; sc1 = sc1 > 0.f ? sc1 : NEG_SLOPE * sc1;
            float sc2 = hl.z + hrv.z + he.z; sc2 = sc2 > 0.f ? sc2 : NEG_SLOPE * sc2;
            float sc3 = hl.w + hrv.w + he.w; sc3 = sc3 > 0.f ? sc3 : NEG_SLOPE * sc3;
            p0 = __expf(sc0 - m0); p1 = __expf(sc1 - m1);
            p2 = __expf(sc2 - m2); p3 = __expf(sc3 - m3);
        }
#pragma unroll
        for (int off = 32; off >= 1; off >>= 1) {
            p0 += __shfl_xor(p0, off); p1 += __shfl_xor(p1, off);
            p2 += __shfl_xor(p2, off); p3 += __shfl_xor(p3, off);
        }
        d0 += p0; d1 += p1; d2 += p2; d3 += p3;
    }

    int myh = lane >> 4;
    float den = myh == 0 ? d0 : myh == 1 ? d1 : myh == 2 ? d2 : d3;
    float inv = (deg > 0) ? 1.f / den : 0.f;

    // ---- pass 3: weighted aggregation ----
    float ax = 0.f, ay = 0.f;
    for (int base = 0; base < deg; base += 64) {
        int el = base + lane;
        float p0 = 0.f, p1 = 0.f, p2 = 0.f, p3 = 0.f;
        int r = 0;
        if (el < deg) {
            int e = eidx[st0 + el];
            r = row[e];
            float4 hl = *(const float4*)&h_l[(size_t)r * 4];
            float4 he = *(const float4*)&h_e_t[(size_t)etype[e] * 4];
            float sc0 = hl.x + hrv.x + he.x; sc0 = sc0 > 0.f ? sc0 : NEG_SLOPE * sc0;
            float sc1 = hl.y + hrv.y + he.y; sc1 = sc1 > 0.f ? sc1 : NEG_SLOPE * sc1;
            float sc2 = hl.z + hrv.z + he.z; sc2 = sc2 > 0.f ? sc2 : NEG_SLOPE * sc2;
            float sc3 = hl.w + hrv.w + he.w; sc3 = sc3 > 0.f ? sc3 : NEG_SLOPE * sc3;
            p0 = __expf(sc0 - m0); p1 = __expf(sc1 - m1);
            p2 = __expf(sc2 - m2); p3 = __expf(sc3 - m3);
        }
        int cmax = (deg - base < 64) ? (deg - base) : 64;
        for (int q = 0; q < cmax; ++q) {
            int rq = __shfl(r, q);
            float a0 = __shfl(p0, q), a1 = __shfl(p1, q);
            float a2 = __shfl(p2, q), a3 = __shfl(p3, q);
            float aq = myh == 0 ? a0 : myh == 1 ? a1 : myh == 2 ? a2 : a3;
            float2 ev = *(const float2*)&emb[(size_t)rq * 128 + lane * 2];
            ax += aq * ev.x;
            ay += aq * ev.y;
        }
    }
    ax *= inv; ay *= inv;

    // ---- epilogue: transpose to d-major, + residual, ELU ----
    int j0 = lane * 2;
    int h0 = j0 >> 5, dd0 = j0 & 31;   // j1 = j0+1 shares h0, dd1 = dd0+1
    size_t ob = (size_t)n * 128;
    float o0 = ax + res[ob + dd0 * 4 + h0];
    float o1 = ay + res[ob + (dd0 + 1) * 4 + h0];
    out[ob + dd0 * 4 + h0] = o0 > 0.f ? o0 : expm1f(o0);
    out[ob + (dd0 + 1) * 4 + h0] = o1 > 0.f ? o1 : expm1f(o1);
}

// ---------------------------------------------------------------------------
extern "C" void kernel_launch(void* const* d_in, const int* in_sizes, int n_in,
                              void* d_out, int out_size, void* d_ws, size_t ws_size,
                              hipStream_t stream)
{
    const float* h        = (const float*)d_in[0];
    const float* W        = (const float*)d_in[1];
    const float* edge_emb = (const float*)d_in[2];
    const float* W_r      = (const float*)d_in[3];
    const float* a_l      = (const float*)d_in[4];
    const float* a_r      = (const float*)d_in[5];
    const float* a_e      = (const float*)d_in[6];
    const float* res_w    = (const float*)d_in[7];
    const float* res_b    = (const float*)d_in[8];
    const int*   row      = (const int*)d_in[9];
    const int*   col      = (const int*)d_in[10];
    const int*   etype    = (const int*)d_in[11];
    float* out = (float*)d_out;

    int N = in_sizes[0] / IN_DIM;
    int E = in_sizes[9];
    int T = in_sizes[2] / EDIM;

    char* ws = (char*)d_ws;
    size_t off = 0;
    auto alloc = [&](size_t bytes) -> char* {
        char* p = ws + off;
        off = (off + bytes + 255) & ~(size_t)255;
        return p;
    };
    float* emb   = (float*)alloc((size_t)N * 128 * 4);
    float* res   = (float*)alloc((size_t)N * 128 * 4);
    float* h_l   = (float*)alloc((size_t)N * 4 * 4);
    float* h_r   = (float*)alloc((size_t)N * 4 * 4);
    float* h_e_t = (float*)alloc((size_t)T * 4 * 4);
    int* starts  = (int*)alloc((size_t)(N + 1) * 4);
    int* cursor  = (int*)alloc((size_t)N * 4);
    int* bsum    = (int*)alloc(256 * 4);
    int* boff    = (int*)alloc(256 * 4);
    int* eidxb   = (int*)alloc((size_t)E * 4);

    int nb  = (N + 255) / 256;
    int neb = (E + 255) / 256;

    hipLaunchKernelGGL(k_edge_type, dim3(1), dim3(T * 128), 0, stream,
                       edge_emb, W_r, a_e, h_e_t);
    hipLaunchKernelGGL(k_gemm, dim3((N + 127) / 128, 2), dim3(256), 0, stream,
                       h, W, res_w, res_b, emb, res, N);
    hipLaunchKernelGGL(k_rowdots, dim3((N + 3) / 4), dim3(256), 0, stream,
                       emb, a_l, a_r, h_l, h_r, N);
    hipLaunchKernelGGL(k_zero, dim3(nb), dim3(256), 0, stream, cursor, N);
    hipLaunchKernelGGL(k_hist, dim3(neb), dim3(256), 0, stream, col, cursor, E);
    hipLaunchKernelGGL(k_scan1, dim3(nb), dim3(256), 0, stream, cursor, starts, bsum, N);
    hipLaunchKernelGGL(k_scan2, dim3(1), dim3(256), 0, stream, bsum, boff, nb);
    hipLaunchKernelGGL(k_scan3, dim3(nb), dim3(256), 0, stream, starts, boff, cursor, N, E);
    hipLaunchKernelGGL(k_fill, dim3(neb), dim3(256), 0, stream, col, cursor, eidxb, E);
    hipLaunchKernelGGL(k_aggregate, dim3((N + 3) / 4), dim3(256), 0, stream,
                       eidxb, starts, row, etype, h_l, h_r, h_e_t, emb, res, out, N);
}

// Round 2
// 268.629 us; speedup vs baseline: 1.0925x; 1.0925x over previous
//
#include <hip/hip_runtime.h>
#include <math.h>

#define IN_DIM 128
#define NH 4
#define DD 32
#define EDIM 32
#define NEG_SLOPE 0.2f

// ---------------------------------------------------------------------------
// h_e_t[t,h] = sum_k a_e[h,k] * (sum_e edge_emb[t,e] * W_r[t,e,h*32+k])
__global__ void k_edge_type(const float* __restrict__ edge_emb,
                            const float* __restrict__ W_r,
                            const float* __restrict__ a_e,
                            float* __restrict__ h_e_t)
{
    int tid = threadIdx.x;
    int t = tid >> 7;
    int rem = tid & 127;
    int k = rem & 31;
    int h = rem >> 5;
    float v = 0.f;
#pragma unroll
    for (int e = 0; e < EDIM; ++e)
        v += edge_emb[t * EDIM + e] * W_r[(size_t)(t * EDIM + e) * 128 + rem];
    v *= a_e[rem];
#pragma unroll
    for (int off = 16; off >= 1; off >>= 1)
        v += __shfl_xor(v, off);
    if (k == 0) h_e_t[t * NH + h] = v;
}

// ---------------------------------------------------------------------------
// C = A @ B (+bias).  Tile 128x128, 8x8/thread.
// blockIdx.y == 0 -> W -> emb, with fused h_l/h_r epilogue.
// blockIdx.y == 1 -> res_w (+res_b) -> res.
__global__ __launch_bounds__(256) void k_gemm(
    const float* __restrict__ A, const float* __restrict__ W,
    const float* __restrict__ Rw, const float* __restrict__ Rb,
    const float* __restrict__ a_l, const float* __restrict__ a_r,
    float* __restrict__ Emb, float* __restrict__ Res,
    float* __restrict__ h_l, float* __restrict__ h_r, int M)
{
    const float* B = (blockIdx.y == 0) ? W : Rw;
    float* C = (blockIdx.y == 0) ? Emb : Res;
    __shared__ float As[16][128];   // [k][m]
    __shared__ float Bs[16][128];   // [k][n]
    int tid = threadIdx.x;
    int tx = tid & 15, ty = tid >> 4;
    int m0 = blockIdx.x * 128;
    float acc[8][8];
#pragma unroll
    for (int i = 0; i < 8; ++i)
#pragma unroll
        for (int j = 0; j < 8; ++j) acc[i][j] = 0.f;

    for (int k0 = 0; k0 < 128; k0 += 16) {
#pragma unroll
        for (int i = 0; i < 2; ++i) {
            int idx = tid * 2 + i;            // 0..511
            int ar = idx >> 2, ac = (idx & 3) << 2;
            float4 v = make_float4(0.f, 0.f, 0.f, 0.f);
            if (m0 + ar < M) v = *(const float4*)&A[(size_t)(m0 + ar) * 128 + k0 + ac];
            As[ac + 0][ar] = v.x; As[ac + 1][ar] = v.y;
            As[ac + 2][ar] = v.z; As[ac + 3][ar] = v.w;
            int br = idx >> 5, bc = (idx & 31) << 2;
            *(float4*)&Bs[br][bc] = *(const float4*)&B[(size_t)(k0 + br) * 128 + bc];
        }
        __syncthreads();
#pragma unroll
        for (int k = 0; k < 16; ++k) {
            float a[8], b[8];
            *(float4*)&a[0] = *(const float4*)&As[k][ty * 8];
            *(float4*)&a[4] = *(const float4*)&As[k][ty * 8 + 4];
            *(float4*)&b[0] = *(const float4*)&Bs[k][tx * 8];
            *(float4*)&b[4] = *(const float4*)&Bs[k][tx * 8 + 4];
#pragma unroll
            for (int i = 0; i < 8; ++i)
#pragma unroll
                for (int j = 0; j < 8; ++j) acc[i][j] += a[i] * b[j];
        }
        __syncthreads();
    }
    bool bias = (blockIdx.y == 1);
#pragma unroll
    for (int i = 0; i < 8; ++i) {
        int r = m0 + ty * 8 + i;
        if (r < M) {
            float4 o0, o1;
            o0.x = acc[i][0] + (bias ? Rb[tx * 8 + 0] : 0.f);
            o0.y = acc[i][1] + (bias ? Rb[tx * 8 + 1] : 0.f);
            o0.z = acc[i][2] + (bias ? Rb[tx * 8 + 2] : 0.f);
            o0.w = acc[i][3] + (bias ? Rb[tx * 8 + 3] : 0.f);
            o1.x = acc[i][4] + (bias ? Rb[tx * 8 + 4] : 0.f);
            o1.y = acc[i][5] + (bias ? Rb[tx * 8 + 5] : 0.f);
            o1.z = acc[i][6] + (bias ? Rb[tx * 8 + 6] : 0.f);
            o1.w = acc[i][7] + (bias ? Rb[tx * 8 + 7] : 0.f);
            *(float4*)&C[(size_t)r * 128 + tx * 8] = o0;
            *(float4*)&C[(size_t)r * 128 + tx * 8 + 4] = o1;
        }
    }
    // fused h_l / h_r: h_l[n,h] = sum over this row's cols of a_l[j]*emb[n,j]
    if (blockIdx.y == 0) {
        float all[8], arr[8];
#pragma unroll
        for (int j = 0; j < 8; ++j) {
            all[j] = a_l[tx * 8 + j];
            arr[j] = a_r[tx * 8 + j];
        }
        int head = tx >> 2;              // cols tx*8.. lie in head tx/4
#pragma unroll
        for (int i = 0; i < 8; ++i) {
            float vl = 0.f, vr = 0.f;
#pragma unroll
            for (int j = 0; j < 8; ++j) {
                vl += all[j] * acc[i][j];
                vr += arr[j] * acc[i][j];
            }
            vl += __shfl_xor(vl, 1); vl += __shfl_xor(vl, 2);
            vr += __shfl_xor(vr, 1); vr += __shfl_xor(vr, 2);
            int r = m0 + ty * 8 + i;
            if ((tx & 3) == 0 && r < M) {
                h_l[(size_t)r * 4 + head] = vl;
                h_r[(size_t)r * 4 + head] = vr;
            }
        }
    }
}

// ---------------------------------------------------------------------------
__global__ void k_zero(int* p, int n) {
    int i = blockIdx.x * blockDim.x + threadIdx.x;
    if (i < n) p[i] = 0;
}

__global__ void k_hist(const int* __restrict__ col, int* __restrict__ cnt, int E) {
    int i = blockIdx.x * blockDim.x + threadIdx.x;
    if (i < E) atomicAdd(&cnt[col[i]], 1);
}

__global__ void k_scan1(const int* __restrict__ cnt, int* __restrict__ starts,
                        int* __restrict__ bsum, int N)
{
    __shared__ int sh[256];
    int t = threadIdx.x, n = blockIdx.x * 256 + t;
    int v = (n < N) ? cnt[n] : 0;
    sh[t] = v; __syncthreads();
    for (int off = 1; off < 256; off <<= 1) {
        int y = (t >= off) ? sh[t - off] : 0;
        __syncthreads();
        sh[t] += y;
        __syncthreads();
    }
    if (n < N) starts[n] = sh[t] - v;
    if (t == 255) bsum[blockIdx.x] = sh[255];
}

__global__ void k_scan2(const int* __restrict__ bsum, int* __restrict__ boff, int nb)
{
    __shared__ int sh[256];
    int t = threadIdx.x;
    int v = (t < nb) ? bsum[t] : 0;
    sh[t] = v; __syncthreads();
    for (int off = 1; off < 256; off <<= 1) {
        int y = (t >= off) ? sh[t - off] : 0;
        __syncthreads();
        sh[t] += y;
        __syncthreads();
    }
    if (t < nb) boff[t] = sh[t] - v;
}

__global__ void k_scan3(int* __restrict__ starts, const int* __restrict__ boff,
                        int* __restrict__ cursor, int N, int E)
{
    int t = threadIdx.x, n = blockIdx.x * 256 + t;
    if (n < N) {
        int st = starts[n] + boff[blockIdx.x];
        starts[n] = st;
        cursor[n] = st;
    }
    if (n == 0) starts[N] = E;
}

__global__ void k_fill(const int* __restrict__ col, int* __restrict__ cursor,
                       int* __restrict__ eidx, int E)
{
    int i = blockIdx.x * blockDim.x + threadIdx.x;
    if (i < E) {
        int pos = atomicAdd(&cursor[col[i]], 1);
        eidx[pos] = i;
    }
}

// ---------------------------------------------------------------------------
// 8-wide MLP gather+accumulate: for edges q=0..cmax-1 (data lives in lanes),
// ax/ay += alpha[q] * emb[row[q]][lane*2 .. +1]
__device__ __forceinline__ void gather_accum(
    const float* __restrict__ emb, int lane, int myh,
    int r, float p0, float p1, float p2, float p3, int cmax,
    float& ax, float& ay)
{
    int q = 0;
    for (; q + 8 <= cmax; q += 8) {
        int rq[8]; float aq[8];
#pragma unroll
        for (int u = 0; u < 8; ++u) {
            rq[u] = __shfl(r, q + u);
            float a0 = __shfl(p0, q + u), a1 = __shfl(p1, q + u);
            float a2 = __shfl(p2, q + u), a3 = __shfl(p3, q + u);
            aq[u] = myh == 0 ? a0 : myh == 1 ? a1 : myh == 2 ? a2 : a3;
        }
        float2 ev[8];
#pragma unroll
        for (int u = 0; u < 8; ++u)
            ev[u] = *(const float2*)&emb[(size_t)rq[u] * 128 + lane * 2];
#pragma unroll
        for (int u = 0; u < 8; ++u) { ax += aq[u] * ev[u].x; ay += aq[u] * ev[u].y; }
    }
    for (; q < cmax; ++q) {
        int rq = __shfl(r, q);
        float a0 = __shfl(p0, q), a1 = __shfl(p1, q);
        float a2 = __shfl(p2, q), a3 = __shfl(p3, q);
        float aq = myh == 0 ? a0 : myh == 1 ? a1 : myh == 2 ? a2 : a3;
        float2 ev = *(const float2*)&emb[(size_t)rq * 128 + lane * 2];
        ax += aq * ev.x; ay += aq * ev.y;
    }
}

// ---------------------------------------------------------------------------
// One wave per destination node. Fast path (deg<=64, ~always at mean deg 16):
// scores stay in registers, single pass over edge metadata.
__global__ __launch_bounds__(256) void k_aggregate(
    const int* __restrict__ eidx, const int* __restrict__ starts,
    const int* __restrict__ row, const int* __restrict__ etype,
    const float* __restrict__ h_l, const float* __restrict__ h_r,
    const float* __restrict__ h_e_t, const float* __restrict__ emb,
    const float* __restrict__ res, float* __restrict__ out, int N)
{
    int n = (blockIdx.x * blockDim.x + threadIdx.x) >> 6;
    if (n >= N) return;
    int lane = threadIdx.x & 63;
    int st0 = starts[n];
    int deg = starts[n + 1] - st0;
    float4 hrv = *(const float4*)&h_r[(size_t)n * 4];
    int myh = lane >> 4;
    float ax = 0.f, ay = 0.f;
    float inv = 0.f;

    if (deg <= 64) {
        // ---- single-chunk register-resident path ----
        int r = 0;
        float sc0 = -INFINITY, sc1 = -INFINITY, sc2 = -INFINITY, sc3 = -INFINITY;
        bool act = lane < deg;
        if (act) {
            int e = eidx[st0 + lane];
            r = row[e];
            float4 hl = *(const float4*)&h_l[(size_t)r * 4];
            float4 he = *(const float4*)&h_e_t[(size_t)etype[e] * 4];
            sc0 = hl.x + hrv.x + he.x; sc0 = sc0 > 0.f ? sc0 : NEG_SLOPE * sc0;
            sc1 = hl.y + hrv.y + he.y; sc1 = sc1 > 0.f ? sc1 : NEG_SLOPE * sc1;
            sc2 = hl.z + hrv.z + he.z; sc2 = sc2 > 0.f ? sc2 : NEG_SLOPE * sc2;
            sc3 = hl.w + hrv.w + he.w; sc3 = sc3 > 0.f ? sc3 : NEG_SLOPE * sc3;
        }
        float m0 = sc0, m1 = sc1, m2 = sc2, m3 = sc3;
#pragma unroll
        for (int off = 32; off >= 1; off >>= 1) {
            m0 = fmaxf(m0, __shfl_xor(m0, off));
            m1 = fmaxf(m1, __shfl_xor(m1, off));
            m2 = fmaxf(m2, __shfl_xor(m2, off));
            m3 = fmaxf(m3, __shfl_xor(m3, off));
        }
        float p0 = act ? __expf(sc0 - m0) : 0.f;
        float p1 = act ? __expf(sc1 - m1) : 0.f;
        float p2 = act ? __expf(sc2 - m2) : 0.f;
        float p3 = act ? __expf(sc3 - m3) : 0.f;
        float d0 = p0, d1 = p1, d2 = p2, d3 = p3;
#pragma unroll
        for (int off = 32; off >= 1; off >>= 1) {
            d0 += __shfl_xor(d0, off); d1 += __shfl_xor(d1, off);
            d2 += __shfl_xor(d2, off); d3 += __shfl_xor(d3, off);
        }
        float den = myh == 0 ? d0 : myh == 1 ? d1 : myh == 2 ? d2 : d3;
        inv = (deg > 0) ? 1.f / den : 0.f;
        gather_accum(emb, lane, myh, r, p0, p1, p2, p3, deg, ax, ay);
    } else {
        // ---- general chunked 3-pass path (rare) ----
        float m0 = -INFINITY, m1 = -INFINITY, m2 = -INFINITY, m3 = -INFINITY;
        for (int base = 0; base < deg; base += 64) {
            int el = base + lane;
            float sc0 = -INFINITY, sc1 = -INFINITY, sc2 = -INFINITY, sc3 = -INFINITY;
            if (el < deg) {
                int e = eidx[st0 + el];
                float4 hl = *(const float4*)&h_l[(size_t)row[e] * 4];
                float4 he = *(const float4*)&h_e_t[(size_t)etype[e] * 4];
                sc0 = hl.x + hrv.x + he.x; sc0 = sc0 > 0.f ? sc0 : NEG_SLOPE * sc0;
                sc1 = hl.y + hrv.y + he.y; sc1 = sc1 > 0.f ? sc1 : NEG_SLOPE * sc1;
                sc2 = hl.z + hrv.z + he.z; sc2 = sc2 > 0.f ? sc2 : NEG_SLOPE * sc2;
                sc3 = hl.w + hrv.w + he.w; sc3 = sc3 > 0.f ? sc3 : NEG_SLOPE * sc3;
            }
            m0 = fmaxf(m0, sc0); m1 = fmaxf(m1, sc1);
            m2 = fmaxf(m2, sc2); m3 = fmaxf(m3, sc3);
        }
#pragma unroll
        for (int off = 32; off >= 1; off >>= 1) {
            m0 = fmaxf(m0, __shfl_xor(m0, off));
            m1 = fmaxf(m1, __shfl_xor(m1, off));
            m2 = fmaxf(m2, __shfl_xor(m2, off));
            m3 = fmaxf(m3, __shfl_xor(m3, off));
        }
        float d0 = 0.f, d1 = 0.f, d2 = 0.f, d3 = 0.f;
        for (int base = 0; base < deg; base += 64) {
            int el = base + lane;
            if (el < deg) {
                int e = eidx[st0 + el];
                float4 hl = *(const float4*)&h_l[(size_t)row[e] * 4];
                float4 he = *(const float4*)&h_e_t[(size_t)etype[e] * 4];
                float sc0 = hl.x + hrv.x + he.x; sc0 = sc0 > 0.f ? sc0 : NEG_SLOPE * sc0;
                float sc1 = hl.y + hrv.y + he.y; sc1 = sc1 > 0.f ? sc1 : NEG_SLOPE * sc1;
                float sc2 = hl.z + hrv.z + he.z; sc2 = sc2 > 0.f ? sc2 : NEG_SLOPE * sc2;
                float sc3 = hl.w + hrv.w + he.w; sc3 = sc3 > 0.f ? sc3 : NEG_SLOPE * sc3;
                d0 += __expf(sc0 - m0); d1 += __expf(sc1 - m1);
                d2 += __expf(sc2 - m2); d3 += __expf(sc3 - m3);
            }
        }
#pragma unroll
        for (int off = 32; off >= 1; off >>= 1) {
            d0 += __shfl_xor(d0, off); d1 += __shfl_xor(d1, off);
            d2 += __shfl_xor(d2, off); d3 += __shfl_xor(d3, off);
        }
        float den = myh == 0 ? d0 : myh == 1 ? d1 : myh == 2 ? d2 : d3;
        inv = 1.f / den;
        for (int base = 0; base < deg; base += 64) {
            int el = base + lane;
            float p0 = 0.f, p1 = 0.f, p2 = 0.f, p3 = 0.f;
            int r = 0;
            if (el < deg) {
                int e = eidx[st0 + el];
                r = row[e];
                float4 hl = *(const float4*)&h_l[(size_t)r * 4];
                float4 he = *(const float4*)&h_e_t[(size_t)etype[e] * 4];
                float sc0 = hl.x + hrv.x + he.x; sc0 = sc0 > 0.f ? sc0 : NEG_SLOPE * sc0;
                float sc1 = hl.y + hrv.y + he.y; sc1 = sc1 > 0.f ? sc1 : NEG_SLOPE * sc1;
                float sc2 = hl.z + hrv.z + he.z; sc2 = sc2 > 0.f ? sc2 : NEG_SLOPE * sc2;
                float sc3 = hl.w + hrv.w + he.w; sc3 = sc3 > 0.f ? sc3 : NEG_SLOPE * sc3;
                p0 = __expf(sc0 - m0); p1 = __expf(sc1 - m1);
                p2 = __expf(sc2 - m2); p3 = __expf(sc3 - m3);
            }
            int cmax = (deg - base < 64) ? (deg - base) : 64;
            gather_accum(emb, lane, myh, r, p0, p1, p2, p3, cmax, ax, ay);
        }
    }
    ax *= inv; ay *= inv;

    // ---- epilogue: transpose to d-major, + residual, ELU ----
    int j0 = lane * 2;
    int h0 = j0 >> 5, dd0 = j0 & 31;
    size_t ob = (size_t)n * 128;
    float o0 = ax + res[ob + dd0 * 4 + h0];
    float o1 = ay + res[ob + (dd0 + 1) * 4 + h0];
    out[ob + dd0 * 4 + h0] = o0 > 0.f ? o0 : expm1f(o0);
    out[ob + (dd0 + 1) * 4 + h0] = o1 > 0.f ? o1 : expm1f(o1);
}

// ---------------------------------------------------------------------------
extern "C" void kernel_launch(void* const* d_in, const int* in_sizes, int n_in,
                              void* d_out, int out_size, void* d_ws, size_t ws_size,
                              hipStream_t stream)
{
    const float* h        = (const float*)d_in[0];
    const float* W        = (const float*)d_in[1];
    const float* edge_emb = (const float*)d_in[2];
    const float* W_r      = (const float*)d_in[3];
    const float* a_l      = (const float*)d_in[4];
    const float* a_r      = (const float*)d_in[5];
    const float* a_e      = (const float*)d_in[6];
    const float* res_w    = (const float*)d_in[7];
    const float* res_b    = (const float*)d_in[8];
    const int*   row      = (const int*)d_in[9];
    const int*   col      = (const int*)d_in[10];
    const int*   etype    = (const int*)d_in[11];
    float* out = (float*)d_out;

    int N = in_sizes[0] / IN_DIM;
    int E = in_sizes[9];
    int T = in_sizes[2] / EDIM;

    char* ws = (char*)d_ws;
    size_t off = 0;
    auto alloc = [&](size_t bytes) -> char* {
        char* p = ws + off;
        off = (off + bytes + 255) & ~(size_t)255;
        return p;
    };
    float* emb   = (float*)alloc((size_t)N * 128 * 4);
    float* res   = (float*)alloc((size_t)N * 128 * 4);
    float* h_l   = (float*)alloc((size_t)N * 4 * 4);
    float* h_r   = (float*)alloc((size_t)N * 4 * 4);
    float* h_e_t = (float*)alloc((size_t)T * 4 * 4);
    int* starts  = (int*)alloc((size_t)(N + 1) * 4);
    int* cursor  = (int*)alloc((size_t)N * 4);
    int* bsum    = (int*)alloc(256 * 4);
    int* boff    = (int*)alloc(256 * 4);
    int* eidxb   = (int*)alloc((size_t)E * 4);

    int nb  = (N + 255) / 256;
    int neb = (E + 255) / 256;

    hipLaunchKernelGGL(k_edge_type, dim3(1), dim3(T * 128), 0, stream,
                       edge_emb, W_r, a_e, h_e_t);
    hipLaunchKernelGGL(k_gemm, dim3((N + 127) / 128, 2), dim3(256), 0, stream,
                       h, W, res_w, res_b, a_l, a_r, emb, res, h_l, h_r, N);
    hipLaunchKernelGGL(k_zero, dim3(nb), dim3(256), 0, stream, cursor, N);
    hipLaunchKernelGGL(k_hist, dim3(neb), dim3(256), 0, stream, col, cursor, E);
    hipLaunchKernelGGL(k_scan1, dim3(nb), dim3(256), 0, stream, cursor, starts, bsum, N);
    hipLaunchKernelGGL(k_scan2, dim3(1), dim3(256), 0, stream, bsum, boff, nb);
    hipLaunchKernelGGL(k_scan3, dim3(nb), dim3(256), 0, stream, starts, boff, cursor, N, E);
    hipLaunchKernelGGL(k_fill, dim3(neb), dim3(256), 0, stream, col, cursor, eidxb, E);
    hipLaunchKernelGGL(k_aggregate, dim3((N + 3) / 4), dim3(256), 0, stream,
                       eidxb, starts, row, etype, h_l, h_r, h_e_t, emb, res, out, N);
}

// Round 3
// 218.862 us; speedup vs baseline: 1.3409x; 1.2274x over previous
//
#include <hip/hip_runtime.h>
#include <math.h>

#define IN_DIM 128
#define NH 4
#define DD 32
#define EDIM 32
#define NEG_SLOPE 0.2f

typedef __attribute__((ext_vector_type(8))) short short8;
typedef __attribute__((ext_vector_type(4))) float f32x4;

__device__ __forceinline__ unsigned short f2bf(float f) {
    unsigned int x = __builtin_bit_cast(unsigned int, f);
    unsigned int r = (x + 0x7fffu + ((x >> 16) & 1u)) >> 16;
    return (unsigned short)r;
}
__device__ __forceinline__ float bf2f(unsigned short u) {
    unsigned int x = ((unsigned int)u) << 16;
    return __builtin_bit_cast(float, x);
}

// ---------------------------------------------------------------------------
// h_e_t[t,h] = sum_k a_e[h,k] * (sum_e edge_emb[t,e] * W_r[t,e,h*32+k])
__global__ void k_edge_type(const float* __restrict__ edge_emb,
                            const float* __restrict__ W_r,
                            const float* __restrict__ a_e,
                            float* __restrict__ h_e_t)
{
    int tid = threadIdx.x;
    int t = tid >> 7;
    int rem = tid & 127;
    int k = rem & 31;
    int h = rem >> 5;
    float v = 0.f;
#pragma unroll
    for (int e = 0; e < EDIM; ++e)
        v += edge_emb[t * EDIM + e] * W_r[(size_t)(t * EDIM + e) * 128 + rem];
    v *= a_e[rem];
#pragma unroll
    for (int off = 16; off >= 1; off >>= 1)
        v += __shfl_xor(v, off);
    if (k == 0) h_e_t[t * NH + h] = v;
}

// ---------------------------------------------------------------------------
// Transpose + f32->bf16 the two 128x128 weight matrices: Wt[n][k] = W[k][n].
__global__ void k_prep_w(const float* __restrict__ W, const float* __restrict__ Rw,
                         unsigned short* __restrict__ Wt, unsigned short* __restrict__ Rwt)
{
    int idx = blockIdx.x * 256 + threadIdx.x;   // 0..16383
    int n = idx >> 7, k = idx & 127;
    Wt[n * 128 + k]  = f2bf(W[k * 128 + n]);
    Rwt[n * 128 + k] = f2bf(Rw[k * 128 + n]);
}

// ---------------------------------------------------------------------------
// MFMA GEMM: C[64 rows x 128 cols] = A(f32, converted) @ Bt^T, output bf16.
// blockIdx.y==0: Wt -> EmbBf ; blockIdx.y==1: Rwt (+Rb bias) -> ResBf.
// LDS: A-tile 64x128 bf16 (16KB) + B 128x128 bf16 (32KB), both XOR-swizzled
// (byte ^= (row&7)<<4) so ds_read_b128 column-slices are conflict-free (T2).
__global__ __launch_bounds__(256) void k_gemm_mfma(
    const float* __restrict__ A, const unsigned short* __restrict__ Wt,
    const unsigned short* __restrict__ Rwt, const float* __restrict__ Rb,
    unsigned short* __restrict__ EmbBf, unsigned short* __restrict__ ResBf, int M)
{
    __shared__ char lds[49152];                 // [0,16384) A, [16384,49152) B
    const unsigned short* Bt = blockIdx.y ? Rwt : Wt;
    int tid = threadIdx.x;
    int m0 = blockIdx.x * 64;

    // stage B: 128x128 bf16, chunks of 8 elems (16B)
#pragma unroll
    for (int i = 0; i < 8; ++i) {
        int c = tid + 256 * i;                  // 0..2047
        int n = c >> 4, kc = c & 15;
        uint4 v = *(const uint4*)&Bt[n * 128 + kc * 8];
        int b = 16384 + ((n * 256 + kc * 16) ^ ((n & 7) << 4));
        *(uint4*)&lds[b] = v;
    }
    // stage A: 64x128, f32 -> bf16 on the fly
#pragma unroll
    for (int i = 0; i < 4; ++i) {
        int c = tid + 256 * i;                  // 0..1023
        int r = c >> 4, kc = c & 15;
        int grow = m0 + r;
        float4 v0 = make_float4(0.f, 0.f, 0.f, 0.f), v1 = v0;
        if (grow < M) {
            v0 = *(const float4*)&A[(size_t)grow * 128 + kc * 8];
            v1 = *(const float4*)&A[(size_t)grow * 128 + kc * 8 + 4];
        }
        union { unsigned short u[8]; uint4 v; } p;
        p.u[0] = f2bf(v0.x); p.u[1] = f2bf(v0.y); p.u[2] = f2bf(v0.z); p.u[3] = f2bf(v0.w);
        p.u[4] = f2bf(v1.x); p.u[5] = f2bf(v1.y); p.u[6] = f2bf(v1.z); p.u[7] = f2bf(v1.w);
        int b = (r * 256 + kc * 16) ^ ((r & 7) << 4);
        *(uint4*)&lds[b] = p.v;
    }
    __syncthreads();

    int w = tid >> 6, lane = tid & 63;
    int g = lane >> 4, l15 = lane & 15;
    int lrow = w * 16 + l15;

    short8 a[4];
#pragma unroll
    for (int s = 0; s < 4; ++s)
        a[s] = *(const short8*)&lds[(lrow * 256 + s * 64 + g * 16) ^ ((lrow & 7) << 4)];

    f32x4 acc[8];
#pragma unroll
    for (int f = 0; f < 8; ++f) acc[f] = (f32x4){0.f, 0.f, 0.f, 0.f};

#pragma unroll
    for (int f = 0; f < 8; ++f) {
        int n = f * 16 + l15;
        int nsw = (n & 7) << 4;
#pragma unroll
        for (int s = 0; s < 4; ++s) {
            short8 b = *(const short8*)&lds[16384 + ((n * 256 + s * 64 + g * 16) ^ nsw)];
            acc[f] = __builtin_amdgcn_mfma_f32_16x16x32_bf16(a[s], b, acc[f], 0, 0, 0);
        }
    }

    bool isRes = (blockIdx.y != 0);
    unsigned short* Cb = isRes ? ResBf : EmbBf;
#pragma unroll
    for (int f = 0; f < 8; ++f) {
        int col = f * 16 + l15;
        float bias = isRes ? Rb[col] : 0.f;
#pragma unroll
        for (int reg = 0; reg < 4; ++reg) {
            int grow = m0 + w * 16 + g * 4 + reg;
            if (grow < M) Cb[(size_t)grow * 128 + col] = f2bf(acc[f][reg] + bias);
        }
    }
}

// ---------------------------------------------------------------------------
// h_l[n,h] = sum_d a_l[h,d]*emb[n,h,d] from bf16 emb.  One wave per node.
__global__ __launch_bounds__(256) void k_rowdots_bf(
    const unsigned short* __restrict__ embBf, const float* __restrict__ a_l,
    const float* __restrict__ a_r, float* __restrict__ h_l,
    float* __restrict__ h_r, int N)
{
    int n = (blockIdx.x * blockDim.x + threadIdx.x) >> 6;
    if (n >= N) return;
    int lane = threadIdx.x & 63;
    unsigned int ev = *(const unsigned int*)&embBf[(size_t)n * 128 + lane * 2];
    float e0 = bf2f((unsigned short)(ev & 0xffffu));
    float e1 = bf2f((unsigned short)(ev >> 16));
    float2 al = *(const float2*)&a_l[lane * 2];
    float2 ar = *(const float2*)&a_r[lane * 2];
    float vl = e0 * al.x + e1 * al.y;
    float vr = e0 * ar.x + e1 * ar.y;
#pragma unroll
    for (int off = 8; off >= 1; off >>= 1) {
        vl += __shfl_xor(vl, off);
        vr += __shfl_xor(vr, off);
    }
    if ((lane & 15) == 0) {
        int h = lane >> 4;
        h_l[(size_t)n * 4 + h] = vl;
        h_r[(size_t)n * 4 + h] = vr;
    }
}

// ---------------------------------------------------------------------------
__global__ void k_zero(int* p, int n) {
    int i = blockIdx.x * blockDim.x + threadIdx.x;
    if (i < n) p[i] = 0;
}

__global__ void k_hist(const int* __restrict__ col, int* __restrict__ cnt, int E) {
    int i = blockIdx.x * blockDim.x + threadIdx.x;
    if (i < E) atomicAdd(&cnt[col[i]], 1);
}

__global__ void k_scan1(const int* __restrict__ cnt, int* __restrict__ starts,
                        int* __restrict__ bsum, int N)
{
    __shared__ int sh[256];
    int t = threadIdx.x, n = blockIdx.x * 256 + t;
    int v = (n < N) ? cnt[n] : 0;
    sh[t] = v; __syncthreads();
    for (int off = 1; off < 256; off <<= 1) {
        int y = (t >= off) ? sh[t - off] : 0;
        __syncthreads();
        sh[t] += y;
        __syncthreads();
    }
    if (n < N) starts[n] = sh[t] - v;
    if (t == 255) bsum[blockIdx.x] = sh[255];
}

__global__ void k_scan2(const int* __restrict__ bsum, int* __restrict__ boff, int nb)
{
    __shared__ int sh[256];
    int t = threadIdx.x;
    int v = (t < nb) ? bsum[t] : 0;
    sh[t] = v; __syncthreads();
    for (int off = 1; off < 256; off <<= 1) {
        int y = (t >= off) ? sh[t - off] : 0;
        __syncthreads();
        sh[t] += y;
        __syncthreads();
    }
    if (t < nb) boff[t] = sh[t] - v;
}

__global__ void k_scan3(int* __restrict__ starts, const int* __restrict__ boff,
                        int* __restrict__ cursor, int N, int E)
{
    int t = threadIdx.x, n = blockIdx.x * 256 + t;
    if (n < N) {
        int st = starts[n] + boff[blockIdx.x];
        starts[n] = st;
        cursor[n] = st;
    }
    if (n == 0) starts[N] = E;
}

__global__ void k_fill(const int* __restrict__ col, int* __restrict__ cursor,
                       int* __restrict__ eidx, int E)
{
    int i = blockIdx.x * blockDim.x + threadIdx.x;
    if (i < E) {
        int pos = atomicAdd(&cursor[col[i]], 1);
        eidx[pos] = i;
    }
}

// ---------------------------------------------------------------------------
// 8-wide MLP gather+accumulate over bf16 emb rows.
__device__ __forceinline__ void gather_accum(
    const unsigned short* __restrict__ embBf, int lane, int myh,
    int r, float p0, float p1, float p2, float p3, int cmax,
    float& ax, float& ay)
{
    int q = 0;
    for (; q + 8 <= cmax; q += 8) {
        int rq[8]; float aq[8];
#pragma unroll
        for (int u = 0; u < 8; ++u) {
            rq[u] = __shfl(r, q + u);
            float a0 = __shfl(p0, q + u), a1 = __shfl(p1, q + u);
            float a2 = __shfl(p2, q + u), a3 = __shfl(p3, q + u);
            aq[u] = myh == 0 ? a0 : myh == 1 ? a1 : myh == 2 ? a2 : a3;
        }
        unsigned int ev[8];
#pragma unroll
        for (int u = 0; u < 8; ++u)
            ev[u] = *(const unsigned int*)&embBf[(size_t)rq[u] * 128 + lane * 2];
#pragma unroll
        for (int u = 0; u < 8; ++u) {
            ax += aq[u] * bf2f((unsigned short)(ev[u] & 0xffffu));
            ay += aq[u] * bf2f((unsigned short)(ev[u] >> 16));
        }
    }
    for (; q < cmax; ++q) {
        int rq = __shfl(r, q);
        float a0 = __shfl(p0, q), a1 = __shfl(p1, q);
        float a2 = __shfl(p2, q), a3 = __shfl(p3, q);
        float aq = myh == 0 ? a0 : myh == 1 ? a1 : myh == 2 ? a2 : a3;
        unsigned int ev = *(const unsigned int*)&embBf[(size_t)rq * 128 + lane * 2];
        ax += aq * bf2f((unsigned short)(ev & 0xffffu));
        ay += aq * bf2f((unsigned short)(ev >> 16));
    }
}

// ---------------------------------------------------------------------------
// One wave per destination node; fast single-chunk path for deg<=64.
__global__ __launch_bounds__(256) void k_aggregate(
    const int* __restrict__ eidx, const int* __restrict__ starts,
    const int* __restrict__ row, const int* __restrict__ etype,
    const float* __restrict__ h_l, const float* __restrict__ h_r,
    const float* __restrict__ h_e_t, const unsigned short* __restrict__ embBf,
    const unsigned short* __restrict__ resBf, float* __restrict__ out, int N)
{
    int n = (blockIdx.x * blockDim.x + threadIdx.x) >> 6;
    if (n >= N) return;
    int lane = threadIdx.x & 63;
    int st0 = starts[n];
    int deg = starts[n + 1] - st0;
    float4 hrv = *(const float4*)&h_r[(size_t)n * 4];
    int myh = lane >> 4;
    float ax = 0.f, ay = 0.f;
    float inv = 0.f;

    if (deg <= 64) {
        int r = 0;
        float sc0 = -INFINITY, sc1 = -INFINITY, sc2 = -INFINITY, sc3 = -INFINITY;
        bool act = lane < deg;
        if (act) {
            int e = eidx[st0 + lane];
            r = row[e];
            float4 hl = *(const float4*)&h_l[(size_t)r * 4];
            float4 he = *(const float4*)&h_e_t[(size_t)etype[e] * 4];
            sc0 = hl.x + hrv.x + he.x; sc0 = sc0 > 0.f ? sc0 : NEG_SLOPE * sc0;
            sc1 = hl.y + hrv.y + he.y; sc1 = sc1 > 0.f ? sc1 : NEG_SLOPE * sc1;
            sc2 = hl.z + hrv.z + he.z; sc2 = sc2 > 0.f ? sc2 : NEG_SLOPE * sc2;
            sc3 = hl.w + hrv.w + he.w; sc3 = sc3 > 0.f ? sc3 : NEG_SLOPE * sc3;
        }
        float m0 = sc0, m1 = sc1, m2 = sc2, m3 = sc3;
#pragma unroll
        for (int off = 32; off >= 1; off >>= 1) {
            m0 = fmaxf(m0, __shfl_xor(m0, off));
            m1 = fmaxf(m1, __shfl_xor(m1, off));
            m2 = fmaxf(m2, __shfl_xor(m2, off));
            m3 = fmaxf(m3, __shfl_xor(m3, off));
        }
        float p0 = act ? __expf(sc0 - m0) : 0.f;
        float p1 = act ? __expf(sc1 - m1) : 0.f;
        float p2 = act ? __expf(sc2 - m2) : 0.f;
        float p3 = act ? __expf(sc3 - m3) : 0.f;
        float d0 = p0, d1 = p1, d2 = p2, d3 = p3;
#pragma unroll
        for (int off = 32; off >= 1; off >>= 1) {
            d0 += __shfl_xor(d0, off); d1 += __shfl_xor(d1, off);
            d2 += __shfl_xor(d2, off); d3 += __shfl_xor(d3, off);
        }
        float den = myh == 0 ? d0 : myh == 1 ? d1 : myh == 2 ? d2 : d3;
        inv = (deg > 0) ? 1.f / den : 0.f;
        gather_accum(embBf, lane, myh, r, p0, p1, p2, p3, deg, ax, ay);
    } else {
        float m0 = -INFINITY, m1 = -INFINITY, m2 = -INFINITY, m3 = -INFINITY;
        for (int base = 0; base < deg; base += 64) {
            int el = base + lane;
            float sc0 = -INFINITY, sc1 = -INFINITY, sc2 = -INFINITY, sc3 = -INFINITY;
            if (el < deg) {
                int e = eidx[st0 + el];
                float4 hl = *(const float4*)&h_l[(size_t)row[e] * 4];
                float4 he = *(const float4*)&h_e_t[(size_t)etype[e] * 4];
                sc0 = hl.x + hrv.x + he.x; sc0 = sc0 > 0.f ? sc0 : NEG_SLOPE * sc0;
                sc1 = hl.y + hrv.y + he.y; sc1 = sc1 > 0.f ? sc1 : NEG_SLOPE * sc1;
                sc2 = hl.z + hrv.z + he.z; sc2 = sc2 > 0.f ? sc2 : NEG_SLOPE * sc2;
                sc3 = hl.w + hrv.w + he.w; sc3 = sc3 > 0.f ? sc3 : NEG_SLOPE * sc3;
            }
            m0 = fmaxf(m0, sc0); m1 = fmaxf(m1, sc1);
            m2 = fmaxf(m2, sc2); m3 = fmaxf(m3, sc3);
        }
#pragma unroll
        for (int off = 32; off >= 1; off >>= 1) {
            m0 = fmaxf(m0, __shfl_xor(m0, off));
            m1 = fmaxf(m1, __shfl_xor(m1, off));
            m2 = fmaxf(m2, __shfl_xor(m2, off));
            m3 = fmaxf(m3, __shfl_xor(m3, off));
        }
        float d0 = 0.f, d1 = 0.f, d2 = 0.f, d3 = 0.f;
        for (int base = 0; base < deg; base += 64) {
            int el = base + lane;
            if (el < deg) {
                int e = eidx[st0 + el];
                float4 hl = *(const float4*)&h_l[(size_t)row[e] * 4];
                float4 he = *(const float4*)&h_e_t[(size_t)etype[e] * 4];
                float sc0 = hl.x + hrv.x + he.x; sc0 = sc0 > 0.f ? sc0 : NEG_SLOPE * sc0;
                float sc1 = hl.y + hrv.y + he.y; sc1 = sc1 > 0.f ? sc1 : NEG_SLOPE * sc1;
                float sc2 = hl.z + hrv.z + he.z; sc2 = sc2 > 0.f ? sc2 : NEG_SLOPE * sc2;
                float sc3 = hl.w + hrv.w + he.w; sc3 = sc3 > 0.f ? sc3 : NEG_SLOPE * sc3;
                d0 += __expf(sc0 - m0); d1 += __expf(sc1 - m1);
                d2 += __expf(sc2 - m2); d3 += __expf(sc3 - m3);
            }
        }
#pragma unroll
        for (int off = 32; off >= 1; off >>= 1) {
            d0 += __shfl_xor(d0, off); d1 += __shfl_xor(d1, off);
            d2 += __shfl_xor(d2, off); d3 += __shfl_xor(d3, off);
        }
        float den = myh == 0 ? d0 : myh == 1 ? d1 : myh == 2 ? d2 : d3;
        inv = 1.f / den;
        for (int base = 0; base < deg; base += 64) {
            int el = base + lane;
            float p0 = 0.f, p1 = 0.f, p2 = 0.f, p3 = 0.f;
            int r = 0;
            if (el < deg) {
                int e = eidx[st0 + el];
                r = row[e];
                float4 hl = *(const float4*)&h_l[(size_t)r * 4];
                float4 he = *(const float4*)&h_e_t[(size_t)etype[e] * 4];
                float sc0 = hl.x + hrv.x + he.x; sc0 = sc0 > 0.f ? sc0 : NEG_SLOPE * sc0;
                float sc1 = hl.y + hrv.y + he.y; sc1 = sc1 > 0.f ? sc1 : NEG_SLOPE * sc1;
                float sc2 = hl.z + hrv.z + he.z; sc2 = sc2 > 0.f ? sc2 : NEG_SLOPE * sc2;
                float sc3 = hl.w + hrv.w + he.w; sc3 = sc3 > 0.f ? sc3 : NEG_SLOPE * sc3;
                p0 = __expf(sc0 - m0); p1 = __expf(sc1 - m1);
                p2 = __expf(sc2 - m2); p3 = __expf(sc3 - m3);
            }
            int cmax = (deg - base < 64) ? (deg - base) : 64;
            gather_accum(embBf, lane, myh, r, p0, p1, p2, p3, cmax, ax, ay);
        }
    }
    ax *= inv; ay *= inv;

    // epilogue: transpose to d-major, + residual (bf16), ELU
    int j0 = lane * 2;
    int h0 = j0 >> 5, dd0 = j0 & 31;
    size_t ob = (size_t)n * 128;
    float o0 = ax + bf2f(resBf[ob + dd0 * 4 + h0]);
    float o1 = ay + bf2f(resBf[ob + (dd0 + 1) * 4 + h0]);
    out[ob + dd0 * 4 + h0] = o0 > 0.f ? o0 : expm1f(o0);
    out[ob + (dd0 + 1) * 4 + h0] = o1 > 0.f ? o1 : expm1f(o1);
}

// ---------------------------------------------------------------------------
extern "C" void kernel_launch(void* const* d_in, const int* in_sizes, int n_in,
                              void* d_out, int out_size, void* d_ws, size_t ws_size,
                              hipStream_t stream)
{
    const float* h        = (const float*)d_in[0];
    const float* W        = (const float*)d_in[1];
    const float* edge_emb = (const float*)d_in[2];
    const float* W_r      = (const float*)d_in[3];
    const float* a_l      = (const float*)d_in[4];
    const float* a_r      = (const float*)d_in[5];
    const float* a_e      = (const float*)d_in[6];
    const float* res_w    = (const float*)d_in[7];
    const float* res_b    = (const float*)d_in[8];
    const int*   row      = (const int*)d_in[9];
    const int*   col      = (const int*)d_in[10];
    const int*   etype    = (const int*)d_in[11];
    float* out = (float*)d_out;

    int N = in_sizes[0] / IN_DIM;
    int E = in_sizes[9];
    int T = in_sizes[2] / EDIM;

    char* ws = (char*)d_ws;
    size_t off = 0;
    auto alloc = [&](size_t bytes) -> char* {
        char* p = ws + off;
        off = (off + bytes + 255) & ~(size_t)255;
        return p;
    };
    unsigned short* embBf = (unsigned short*)alloc((size_t)N * 128 * 2);
    unsigned short* resBf = (unsigned short*)alloc((size_t)N * 128 * 2);
    unsigned short* Wt    = (unsigned short*)alloc((size_t)128 * 128 * 2);
    unsigned short* Rwt   = (unsigned short*)alloc((size_t)128 * 128 * 2);
    float* h_l   = (float*)alloc((size_t)N * 4 * 4);
    float* h_r   = (float*)alloc((size_t)N * 4 * 4);
    float* h_e_t = (float*)alloc((size_t)T * 4 * 4);
    int* starts  = (int*)alloc((size_t)(N + 1) * 4);
    int* cursor  = (int*)alloc((size_t)N * 4);
    int* bsum    = (int*)alloc(256 * 4);
    int* boff    = (int*)alloc(256 * 4);
    int* eidxb   = (int*)alloc((size_t)E * 4);

    int nb  = (N + 255) / 256;
    int neb = (E + 255) / 256;

    hipLaunchKernelGGL(k_edge_type, dim3(1), dim3(T * 128), 0, stream,
                       edge_emb, W_r, a_e, h_e_t);
    hipLaunchKernelGGL(k_prep_w, dim3(64), dim3(256), 0, stream, W, res_w, Wt, Rwt);
    hipLaunchKernelGGL(k_gemm_mfma, dim3((N + 63) / 64, 2), dim3(256), 0, stream,
                       h, Wt, Rwt, res_b, embBf, resBf, N);
    hipLaunchKernelGGL(k_rowdots_bf, dim3((N + 3) / 4), dim3(256), 0, stream,
                       embBf, a_l, a_r, h_l, h_r, N);
    hipLaunchKernelGGL(k_zero, dim3(nb), dim3(256), 0, stream, cursor, N);
    hipLaunchKernelGGL(k_hist, dim3(neb), dim3(256), 0, stream, col, cursor, E);
    hipLaunchKernelGGL(k_scan1, dim3(nb), dim3(256), 0, stream, cursor, starts, bsum, N);
    hipLaunchKernelGGL(k_scan2, dim3(1), dim3(256), 0, stream, bsum, boff, nb);
    hipLaunchKernelGGL(k_scan3, dim3(nb), dim3(256), 0, stream, starts, boff, cursor, N, E);
    hipLaunchKernelGGL(k_fill, dim3(neb), dim3(256), 0, stream, col, cursor, eidxb, E);
    hipLaunchKernelGGL(k_aggregate, dim3((N + 3) / 4), dim3(256), 0, stream,
                       eidxb, starts, row, etype, h_l, h_r, h_e_t, embBf, resBf, out, N);
}

// Round 4
// 211.923 us; speedup vs baseline: 1.3848x; 1.0327x over previous
//
#include <hip/hip_runtime.h>
#include <math.h>

#define IN_DIM 128
#define NH 4
#define DD 32
#define EDIM 32
#define NEG_SLOPE 0.2f

typedef __attribute__((ext_vector_type(8))) short short8;
typedef __attribute__((ext_vector_type(4))) float f32x4;

__device__ __forceinline__ unsigned short f2bf(float f) {
    unsigned int x = __builtin_bit_cast(unsigned int, f);
    unsigned int r = (x + 0x7fffu + ((x >> 16) & 1u)) >> 16;
    return (unsigned short)r;
}
__device__ __forceinline__ float bf2f(unsigned short u) {
    unsigned int x = ((unsigned int)u) << 16;
    return __builtin_bit_cast(float, x);
}

// ---------------------------------------------------------------------------
// h_e_t[t,h] = sum_k a_e[h,k] * (sum_e edge_emb[t,e] * W_r[t,e,h*32+k])
// One block per edge type (T blocks x 128 threads).
__global__ void k_edge_type(const float* __restrict__ edge_emb,
                            const float* __restrict__ W_r,
                            const float* __restrict__ a_e,
                            float* __restrict__ h_e_t)
{
    int t = blockIdx.x;
    int rem = threadIdx.x;     // 0..127 = h*32+k
    int k = rem & 31;
    int h = rem >> 5;
    float v = 0.f;
#pragma unroll
    for (int e = 0; e < EDIM; ++e)
        v += edge_emb[t * EDIM + e] * W_r[(size_t)(t * EDIM + e) * 128 + rem];
    v *= a_e[rem];
#pragma unroll
    for (int off = 16; off >= 1; off >>= 1)
        v += __shfl_xor(v, off);
    if (k == 0) h_e_t[t * NH + h] = v;
}

// ---------------------------------------------------------------------------
// Transpose + f32->bf16 the two 128x128 weight matrices: Wt[n][k] = W[k][n].
__global__ void k_prep_w(const float* __restrict__ W, const float* __restrict__ Rw,
                         unsigned short* __restrict__ Wt, unsigned short* __restrict__ Rwt)
{
    int idx = blockIdx.x * 256 + threadIdx.x;   // 0..16383
    int n = idx >> 7, k = idx & 127;
    Wt[n * 128 + k]  = f2bf(W[k * 128 + n]);
    Rwt[n * 128 + k] = f2bf(Rw[k * 128 + n]);
}

// ---------------------------------------------------------------------------
// MFMA GEMM: C[64 rows x 128 cols] = A(f32, converted) @ Bt^T, output bf16.
// blockIdx.y==0: Wt -> EmbBf, plus fused h_l/h_r epilogue from in-register acc.
// blockIdx.y==1: Rwt (+Rb bias) -> ResBf.
__global__ __launch_bounds__(256) void k_gemm_mfma(
    const float* __restrict__ A, const unsigned short* __restrict__ Wt,
    const unsigned short* __restrict__ Rwt, const float* __restrict__ Rb,
    const float* __restrict__ a_l, const float* __restrict__ a_r,
    unsigned short* __restrict__ EmbBf, unsigned short* __restrict__ ResBf,
    float* __restrict__ h_l, float* __restrict__ h_r, int M)
{
    __shared__ char lds[49152];                 // [0,16384) A, [16384,49152) B
    const unsigned short* Bt = blockIdx.y ? Rwt : Wt;
    int tid = threadIdx.x;
    int m0 = blockIdx.x * 64;

    // stage B: 128x128 bf16, swizzled (byte ^= (row&7)<<4)
#pragma unroll
    for (int i = 0; i < 8; ++i) {
        int c = tid + 256 * i;                  // 0..2047
        int n = c >> 4, kc = c & 15;
        uint4 v = *(const uint4*)&Bt[n * 128 + kc * 8];
        int b = 16384 + ((n * 256 + kc * 16) ^ ((n & 7) << 4));
        *(uint4*)&lds[b] = v;
    }
    // stage A: 64x128, f32 -> bf16 on the fly
#pragma unroll
    for (int i = 0; i < 4; ++i) {
        int c = tid + 256 * i;                  // 0..1023
        int r = c >> 4, kc = c & 15;
        int grow = m0 + r;
        float4 v0 = make_float4(0.f, 0.f, 0.f, 0.f), v1 = v0;
        if (grow < M) {
            v0 = *(const float4*)&A[(size_t)grow * 128 + kc * 8];
            v1 = *(const float4*)&A[(size_t)grow * 128 + kc * 8 + 4];
        }
        union { unsigned short u[8]; uint4 v; } p;
        p.u[0] = f2bf(v0.x); p.u[1] = f2bf(v0.y); p.u[2] = f2bf(v0.z); p.u[3] = f2bf(v0.w);
        p.u[4] = f2bf(v1.x); p.u[5] = f2bf(v1.y); p.u[6] = f2bf(v1.z); p.u[7] = f2bf(v1.w);
        int b = (r * 256 + kc * 16) ^ ((r & 7) << 4);
        *(uint4*)&lds[b] = p.v;
    }
    __syncthreads();

    int w = tid >> 6, lane = tid & 63;
    int g = lane >> 4, l15 = lane & 15;
    int lrow = w * 16 + l15;

    short8 a[4];
#pragma unroll
    for (int s = 0; s < 4; ++s)
        a[s] = *(const short8*)&lds[(lrow * 256 + s * 64 + g * 16) ^ ((lrow & 7) << 4)];

    f32x4 acc[8];
#pragma unroll
    for (int f = 0; f < 8; ++f) acc[f] = (f32x4){0.f, 0.f, 0.f, 0.f};

#pragma unroll
    for (int f = 0; f < 8; ++f) {
        int n = f * 16 + l15;
        int nsw = (n & 7) << 4;
#pragma unroll
        for (int s = 0; s < 4; ++s) {
            short8 b = *(const short8*)&lds[16384 + ((n * 256 + s * 64 + g * 16) ^ nsw)];
            acc[f] = __builtin_amdgcn_mfma_f32_16x16x32_bf16(a[s], b, acc[f], 0, 0, 0);
        }
    }

    bool isRes = (blockIdx.y != 0);
    unsigned short* Cb = isRes ? ResBf : EmbBf;
#pragma unroll
    for (int f = 0; f < 8; ++f) {
        int col = f * 16 + l15;
        float bias = isRes ? Rb[col] : 0.f;
#pragma unroll
        for (int reg = 0; reg < 4; ++reg) {
            int grow = m0 + w * 16 + g * 4 + reg;
            if (grow < M) Cb[(size_t)grow * 128 + col] = f2bf(acc[f][reg] + bias);
        }
    }

    // fused h_l/h_r epilogue (emb only): reduce a_l[col]*acc over 16 lanes
    if (!isRes) {
        float alv[8], arv[8];
#pragma unroll
        for (int f = 0; f < 8; ++f) {
            alv[f] = a_l[f * 16 + l15];
            arv[f] = a_r[f * 16 + l15];
        }
#pragma unroll
        for (int reg = 0; reg < 4; ++reg) {
            float4 hl4, hr4;
#pragma unroll
            for (int hh = 0; hh < 4; ++hh) {
                float pl = alv[2 * hh] * acc[2 * hh][reg] + alv[2 * hh + 1] * acc[2 * hh + 1][reg];
                float pr = arv[2 * hh] * acc[2 * hh][reg] + arv[2 * hh + 1] * acc[2 * hh + 1][reg];
#pragma unroll
                for (int off = 8; off >= 1; off >>= 1) {
                    pl += __shfl_xor(pl, off);
                    pr += __shfl_xor(pr, off);
                }
                (&hl4.x)[hh] = pl;
                (&hr4.x)[hh] = pr;
            }
            int grow = m0 + w * 16 + g * 4 + reg;
            if (l15 == 0 && grow < M) {
                *(float4*)&h_l[(size_t)grow * 4] = hl4;
                *(float4*)&h_r[(size_t)grow * 4] = hr4;
            }
        }
    }
}

// ---------------------------------------------------------------------------
__global__ void k_zero(int* p, int n) {
    int i = blockIdx.x * blockDim.x + threadIdx.x;
    if (i < n) p[i] = 0;
}

__global__ void k_hist(const int* __restrict__ col, int* __restrict__ cnt, int E) {
    int i = blockIdx.x * blockDim.x + threadIdx.x;
    if (i < E) atomicAdd(&cnt[col[i]], 1);
}

__global__ void k_scan1(const int* __restrict__ cnt, int* __restrict__ starts,
                        int* __restrict__ bsum, int N)
{
    __shared__ int sh[256];
    int t = threadIdx.x, n = blockIdx.x * 256 + t;
    int v = (n < N) ? cnt[n] : 0;
    sh[t] = v; __syncthreads();
    for (int off = 1; off < 256; off <<= 1) {
        int y = (t >= off) ? sh[t - off] : 0;
        __syncthreads();
        sh[t] += y;
        __syncthreads();
    }
    if (n < N) starts[n] = sh[t] - v;
    if (t == 255) bsum[blockIdx.x] = sh[255];
}

__global__ void k_scan2(const int* __restrict__ bsum, int* __restrict__ boff, int nb)
{
    __shared__ int sh[256];
    int t = threadIdx.x;
    int v = (t < nb) ? bsum[t] : 0;
    sh[t] = v; __syncthreads();
    for (int off = 1; off < 256; off <<= 1) {
        int y = (t >= off) ? sh[t - off] : 0;
        __syncthreads();
        sh[t] += y;
        __syncthreads();
    }
    if (t < nb) boff[t] = sh[t] - v;
}

__global__ void k_scan3(int* __restrict__ starts, const int* __restrict__ boff,
                        int* __restrict__ cursor, int N, int E)
{
    int t = threadIdx.x, n = blockIdx.x * 256 + t;
    if (n < N) {
        int st = starts[n] + boff[blockIdx.x];
        starts[n] = st;
        cursor[n] = st;
    }
    if (n == 0) starts[N] = E;
}

// ---------------------------------------------------------------------------
// Fill CSR with PAYLOAD: srcrow[pos] = row, scl[pos] = h_l[row] + h_e_t[etype].
// Moves aggregate's per-edge random gathers into this streaming kernel.
__global__ void k_fill(const int* __restrict__ row, const int* __restrict__ col,
                       const int* __restrict__ etype, int* __restrict__ cursor,
                       const float* __restrict__ h_l, const float* __restrict__ h_e_t,
                       int* __restrict__ srcrow, float4* __restrict__ scl, int E)
{
    int i = blockIdx.x * blockDim.x + threadIdx.x;
    if (i < E) {
        int c = col[i];
        int pos = atomicAdd(&cursor[c], 1);
        int r = row[i];
        float4 hl = *(const float4*)&h_l[(size_t)r * 4];
        float4 he = *(const float4*)&h_e_t[(size_t)etype[i] * 4];
        srcrow[pos] = r;
        scl[pos] = make_float4(hl.x + he.x, hl.y + he.y, hl.z + he.z, hl.w + he.w);
    }
}

// ---------------------------------------------------------------------------
// 8-wide MLP gather+accumulate over bf16 emb rows.
__device__ __forceinline__ void gather_accum(
    const unsigned short* __restrict__ embBf, int lane, int myh,
    int r, float p0, float p1, float p2, float p3, int cmax,
    float& ax, float& ay)
{
    int q = 0;
    for (; q + 8 <= cmax; q += 8) {
        int rq[8]; float aq[8];
#pragma unroll
        for (int u = 0; u < 8; ++u) {
            rq[u] = __shfl(r, q + u);
            float a0 = __shfl(p0, q + u), a1 = __shfl(p1, q + u);
            float a2 = __shfl(p2, q + u), a3 = __shfl(p3, q + u);
            aq[u] = myh == 0 ? a0 : myh == 1 ? a1 : myh == 2 ? a2 : a3;
        }
        unsigned int ev[8];
#pragma unroll
        for (int u = 0; u < 8; ++u)
            ev[u] = *(const unsigned int*)&embBf[(size_t)rq[u] * 128 + lane * 2];
#pragma unroll
        for (int u = 0; u < 8; ++u) {
            ax += aq[u] * bf2f((unsigned short)(ev[u] & 0xffffu));
            ay += aq[u] * bf2f((unsigned short)(ev[u] >> 16));
        }
    }
    for (; q < cmax; ++q) {
        int rq = __shfl(r, q);
        float a0 = __shfl(p0, q), a1 = __shfl(p1, q);
        float a2 = __shfl(p2, q), a3 = __shfl(p3, q);
        float aq = myh == 0 ? a0 : myh == 1 ? a1 : myh == 2 ? a2 : a3;
        unsigned int ev = *(const unsigned int*)&embBf[(size_t)rq * 128 + lane * 2];
        ax += aq * bf2f((unsigned short)(ev & 0xffffu));
        ay += aq * bf2f((unsigned short)(ev >> 16));
    }
}

// ---------------------------------------------------------------------------
// One wave per destination node; fast single-chunk path for deg<=64.
// All per-edge metadata is coalesced CSR payload; only emb gather is random.
__global__ __launch_bounds__(256) void k_aggregate(
    const int* __restrict__ srcrow, const float4* __restrict__ scl,
    const int* __restrict__ starts, const float* __restrict__ h_r,
    const unsigned short* __restrict__ embBf,
    const unsigned short* __restrict__ resBf, float* __restrict__ out, int N)
{
    int n = (blockIdx.x * blockDim.x + threadIdx.x) >> 6;
    if (n >= N) return;
    int lane = threadIdx.x & 63;
    int st0 = starts[n];
    int deg = starts[n + 1] - st0;
    float4 hrv = *(const float4*)&h_r[(size_t)n * 4];
    int myh = lane >> 4;
    float ax = 0.f, ay = 0.f;
    float inv = 0.f;

    if (deg <= 64) {
        int r = 0;
        float sc0 = -INFINITY, sc1 = -INFINITY, sc2 = -INFINITY, sc3 = -INFINITY;
        bool act = lane < deg;
        if (act) {
            r = srcrow[st0 + lane];
            float4 s = scl[st0 + lane];
            sc0 = s.x + hrv.x; sc0 = sc0 > 0.f ? sc0 : NEG_SLOPE * sc0;
            sc1 = s.y + hrv.y; sc1 = sc1 > 0.f ? sc1 : NEG_SLOPE * sc1;
            sc2 = s.z + hrv.z; sc2 = sc2 > 0.f ? sc2 : NEG_SLOPE * sc2;
            sc3 = s.w + hrv.w; sc3 = sc3 > 0.f ? sc3 : NEG_SLOPE * sc3;
        }
        float m0 = sc0, m1 = sc1, m2 = sc2, m3 = sc3;
#pragma unroll
        for (int off = 32; off >= 1; off >>= 1) {
            m0 = fmaxf(m0, __shfl_xor(m0, off));
            m1 = fmaxf(m1, __shfl_xor(m1, off));
            m2 = fmaxf(m2, __shfl_xor(m2, off));
            m3 = fmaxf(m3, __shfl_xor(m3, off));
        }
        float p0 = act ? __expf(sc0 - m0) : 0.f;
        float p1 = act ? __expf(sc1 - m1) : 0.f;
        float p2 = act ? __expf(sc2 - m2) : 0.f;
        float p3 = act ? __expf(sc3 - m3) : 0.f;
        float d0 = p0, d1 = p1, d2 = p2, d3 = p3;
#pragma unroll
        for (int off = 32; off >= 1; off >>= 1) {
            d0 += __shfl_xor(d0, off); d1 += __shfl_xor(d1, off);
            d2 += __shfl_xor(d2, off); d3 += __shfl_xor(d3, off);
        }
        float den = myh == 0 ? d0 : myh == 1 ? d1 : myh == 2 ? d2 : d3;
        inv = (deg > 0) ? 1.f / den : 0.f;
        gather_accum(embBf, lane, myh, r, p0, p1, p2, p3, deg, ax, ay);
    } else {
        float m0 = -INFINITY, m1 = -INFINITY, m2 = -INFINITY, m3 = -INFINITY;
        for (int base = 0; base < deg; base += 64) {
            int el = base + lane;
            if (el < deg) {
                float4 s = scl[st0 + el];
                float sc0 = s.x + hrv.x; sc0 = sc0 > 0.f ? sc0 : NEG_SLOPE * sc0;
                float sc1 = s.y + hrv.y; sc1 = sc1 > 0.f ? sc1 : NEG_SLOPE * sc1;
                float sc2 = s.z + hrv.z; sc2 = sc2 > 0.f ? sc2 : NEG_SLOPE * sc2;
                float sc3 = s.w + hrv.w; sc3 = sc3 > 0.f ? sc3 : NEG_SLOPE * sc3;
                m0 = fmaxf(m0, sc0); m1 = fmaxf(m1, sc1);
                m2 = fmaxf(m2, sc2); m3 = fmaxf(m3, sc3);
            }
        }
#pragma unroll
        for (int off = 32; off >= 1; off >>= 1) {
            m0 = fmaxf(m0, __shfl_xor(m0, off));
            m1 = fmaxf(m1, __shfl_xor(m1, off));
            m2 = fmaxf(m2, __shfl_xor(m2, off));
            m3 = fmaxf(m3, __shfl_xor(m3, off));
        }
        float d0 = 0.f, d1 = 0.f, d2 = 0.f, d3 = 0.f;
        for (int base = 0; base < deg; base += 64) {
            int el = base + lane;
            if (el < deg) {
                float4 s = scl[st0 + el];
                float sc0 = s.x + hrv.x; sc0 = sc0 > 0.f ? sc0 : NEG_SLOPE * sc0;
                float sc1 = s.y + hrv.y; sc1 = sc1 > 0.f ? sc1 : NEG_SLOPE * sc1;
                float sc2 = s.z + hrv.z; sc2 = sc2 > 0.f ? sc2 : NEG_SLOPE * sc2;
                float sc3 = s.w + hrv.w; sc3 = sc3 > 0.f ? sc3 : NEG_SLOPE * sc3;
                d0 += __expf(sc0 - m0); d1 += __expf(sc1 - m1);
                d2 += __expf(sc2 - m2); d3 += __expf(sc3 - m3);
            }
        }
#pragma unroll
        for (int off = 32; off >= 1; off >>= 1) {
            d0 += __shfl_xor(d0, off); d1 += __shfl_xor(d1, off);
            d2 += __shfl_xor(d2, off); d3 += __shfl_xor(d3, off);
        }
        float den = myh == 0 ? d0 : myh == 1 ? d1 : myh == 2 ? d2 : d3;
        inv = 1.f / den;
        for (int base = 0; base < deg; base += 64) {
            int el = base + lane;
            float p0 = 0.f, p1 = 0.f, p2 = 0.f, p3 = 0.f;
            int r = 0;
            if (el < deg) {
                r = srcrow[st0 + el];
                float4 s = scl[st0 + el];
                float sc0 = s.x + hrv.x; sc0 = sc0 > 0.f ? sc0 : NEG_SLOPE * sc0;
                float sc1 = s.y + hrv.y; sc1 = sc1 > 0.f ? sc1 : NEG_SLOPE * sc1;
                float sc2 = s.z + hrv.z; sc2 = sc2 > 0.f ? sc2 : NEG_SLOPE * sc2;
                float sc3 = s.w + hrv.w; sc3 = sc3 > 0.f ? sc3 : NEG_SLOPE * sc3;
                p0 = __expf(sc0 - m0); p1 = __expf(sc1 - m1);
                p2 = __expf(sc2 - m2); p3 = __expf(sc3 - m3);
            }
            int cmax = (deg - base < 64) ? (deg - base) : 64;
            gather_accum(embBf, lane, myh, r, p0, p1, p2, p3, cmax, ax, ay);
        }
    }
    ax *= inv; ay *= inv;

    // epilogue: transpose to d-major, + residual (bf16), ELU
    int j0 = lane * 2;
    int h0 = j0 >> 5, dd0 = j0 & 31;
    size_t ob = (size_t)n * 128;
    float o0 = ax + bf2f(resBf[ob + dd0 * 4 + h0]);
    float o1 = ay + bf2f(resBf[ob + (dd0 + 1) * 4 + h0]);
    out[ob + dd0 * 4 + h0] = o0 > 0.f ? o0 : expm1f(o0);
    out[ob + (dd0 + 1) * 4 + h0] = o1 > 0.f ? o1 : expm1f(o1);
}

// ---------------------------------------------------------------------------
extern "C" void kernel_launch(void* const* d_in, const int* in_sizes, int n_in,
                              void* d_out, int out_size, void* d_ws, size_t ws_size,
                              hipStream_t stream)
{
    const float* h        = (const float*)d_in[0];
    const float* W        = (const float*)d_in[1];
    const float* edge_emb = (const float*)d_in[2];
    const float* W_r      = (const float*)d_in[3];
    const float* a_l      = (const float*)d_in[4];
    const float* a_r      = (const float*)d_in[5];
    const float* a_e      = (const float*)d_in[6];
    const float* res_w    = (const float*)d_in[7];
    const float* res_b    = (const float*)d_in[8];
    const int*   row      = (const int*)d_in[9];
    const int*   col      = (const int*)d_in[10];
    const int*   etype    = (const int*)d_in[11];
    float* out = (float*)d_out;

    int N = in_sizes[0] / IN_DIM;
    int E = in_sizes[9];
    int T = in_sizes[2] / EDIM;

    char* ws = (char*)d_ws;
    size_t off = 0;
    auto alloc = [&](size_t bytes) -> char* {
        char* p = ws + off;
        off = (off + bytes + 255) & ~(size_t)255;
        return p;
    };
    unsigned short* embBf = (unsigned short*)alloc((size_t)N * 128 * 2);
    unsigned short* resBf = (unsigned short*)alloc((size_t)N * 128 * 2);
    unsigned short* Wt    = (unsigned short*)alloc((size_t)128 * 128 * 2);
    unsigned short* Rwt   = (unsigned short*)alloc((size_t)128 * 128 * 2);
    float* h_l   = (float*)alloc((size_t)N * 4 * 4);
    float* h_r   = (float*)alloc((size_t)N * 4 * 4);
    float* h_e_t = (float*)alloc((size_t)T * 4 * 4);
    int* starts  = (int*)alloc((size_t)(N + 1) * 4);
    int* cursor  = (int*)alloc((size_t)N * 4);
    int* bsum    = (int*)alloc(256 * 4);
    int* boff    = (int*)alloc(256 * 4);
    int* srcrow  = (int*)alloc((size_t)E * 4);
    float4* scl  = (float4*)alloc((size_t)E * 16);

    int nb  = (N + 255) / 256;
    int neb = (E + 255) / 256;

    hipLaunchKernelGGL(k_edge_type, dim3(T), dim3(128), 0, stream,
                       edge_emb, W_r, a_e, h_e_t);
    hipLaunchKernelGGL(k_prep_w, dim3(64), dim3(256), 0, stream, W, res_w, Wt, Rwt);
    hipLaunchKernelGGL(k_gemm_mfma, dim3((N + 63) / 64, 2), dim3(256), 0, stream,
                       h, Wt, Rwt, res_b, a_l, a_r, embBf, resBf, h_l, h_r, N);
    hipLaunchKernelGGL(k_zero, dim3(nb), dim3(256), 0, stream, cursor, N);
    hipLaunchKernelGGL(k_hist, dim3(neb), dim3(256), 0, stream, col, cursor, E);
    hipLaunchKernelGGL(k_scan1, dim3(nb), dim3(256), 0, stream, cursor, starts, bsum, N);
    hipLaunchKernelGGL(k_scan2, dim3(1), dim3(256), 0, stream, bsum, boff, nb);
    hipLaunchKernelGGL(k_scan3, dim3(nb), dim3(256), 0, stream, starts, boff, cursor, N, E);
    hipLaunchKernelGGL(k_fill, dim3(neb), dim3(256), 0, stream,
                       row, col, etype, cursor, h_l, h_e_t, srcrow, scl, E);
    hipLaunchKernelGGL(k_aggregate, dim3((N + 3) / 4), dim3(256), 0, stream,
                       srcrow, scl, starts, h_r, embBf, resBf, out, N);
}

// Round 5
// 176.500 us; speedup vs baseline: 1.6628x; 1.2007x over previous
//
#include <hip/hip_runtime.h>
#include <math.h>

#define IN_DIM 128
#define NH 4
#define DD 32
#define EDIM 32
#define NEG_SLOPE 0.2f

typedef __attribute__((ext_vector_type(8))) short short8;
typedef __attribute__((ext_vector_type(4))) float f32x4;

__device__ __forceinline__ unsigned short f2bf(float f) {
    unsigned int x = __builtin_bit_cast(unsigned int, f);
    unsigned int r = (x + 0x7fffu + ((x >> 16) & 1u)) >> 16;
    return (unsigned short)r;
}
__device__ __forceinline__ float bf2f(unsigned short u) {
    unsigned int x = ((unsigned int)u) << 16;
    return __builtin_bit_cast(float, x);
}

// ---------------------------------------------------------------------------
// h_e_t[t,h] = sum_k a_e[h,k] * (sum_e edge_emb[t,e] * W_r[t,e,h*32+k])
__global__ void k_edge_type(const float* __restrict__ edge_emb,
                            const float* __restrict__ W_r,
                            const float* __restrict__ a_e,
                            float* __restrict__ h_e_t)
{
    int t = blockIdx.x;
    int rem = threadIdx.x;     // 0..127 = h*32+k
    int k = rem & 31;
    int h = rem >> 5;
    float v = 0.f;
#pragma unroll
    for (int e = 0; e < EDIM; ++e)
        v += edge_emb[t * EDIM + e] * W_r[(size_t)(t * EDIM + e) * 128 + rem];
    v *= a_e[rem];
#pragma unroll
    for (int off = 16; off >= 1; off >>= 1)
        v += __shfl_xor(v, off);
    if (k == 0) h_e_t[t * NH + h] = v;
}

// ---------------------------------------------------------------------------
// Transpose + f32->bf16 weights; also zero the CSR cursor (grid-stride).
__global__ void k_prep_w(const float* __restrict__ W, const float* __restrict__ Rw,
                         unsigned short* __restrict__ Wt, unsigned short* __restrict__ Rwt,
                         int* __restrict__ cursor, int N)
{
    int idx = blockIdx.x * 256 + threadIdx.x;   // 0..16383
    int n = idx >> 7, k = idx & 127;
    Wt[n * 128 + k]  = f2bf(W[k * 128 + n]);
    Rwt[n * 128 + k] = f2bf(Rw[k * 128 + n]);
    for (int i = idx; i < N; i += 16384) cursor[i] = 0;
}

// ---------------------------------------------------------------------------
// Fused MFMA GEMM: stage A once; pass 1: B=Wt -> EmbBf (+h_l/h_r epilogue);
// pass 2: restage B=Rwt -> ResBf (+bias).
__global__ __launch_bounds__(256) void k_gemm_mfma(
    const float* __restrict__ A, const unsigned short* __restrict__ Wt,
    const unsigned short* __restrict__ Rwt, const float* __restrict__ Rb,
    const float* __restrict__ a_l, const float* __restrict__ a_r,
    unsigned short* __restrict__ EmbBf, unsigned short* __restrict__ ResBf,
    float* __restrict__ h_l, float* __restrict__ h_r, int M)
{
    __shared__ char lds[49152];                 // [0,16384) A, [16384,49152) B
    int tid = threadIdx.x;
    int m0 = blockIdx.x * 64;

    // stage A: 64x128, f32 -> bf16, swizzled (byte ^= (row&7)<<4)
#pragma unroll
    for (int i = 0; i < 4; ++i) {
        int c = tid + 256 * i;                  // 0..1023
        int r = c >> 4, kc = c & 15;
        int grow = m0 + r;
        float4 v0 = make_float4(0.f, 0.f, 0.f, 0.f), v1 = v0;
        if (grow < M) {
            v0 = *(const float4*)&A[(size_t)grow * 128 + kc * 8];
            v1 = *(const float4*)&A[(size_t)grow * 128 + kc * 8 + 4];
        }
        union { unsigned short u[8]; uint4 v; } p;
        p.u[0] = f2bf(v0.x); p.u[1] = f2bf(v0.y); p.u[2] = f2bf(v0.z); p.u[3] = f2bf(v0.w);
        p.u[4] = f2bf(v1.x); p.u[5] = f2bf(v1.y); p.u[6] = f2bf(v1.z); p.u[7] = f2bf(v1.w);
        int b = (r * 256 + kc * 16) ^ ((r & 7) << 4);
        *(uint4*)&lds[b] = p.v;
    }
    // stage B = Wt
#pragma unroll
    for (int i = 0; i < 8; ++i) {
        int c = tid + 256 * i;                  // 0..2047
        int n = c >> 4, kc = c & 15;
        uint4 v = *(const uint4*)&Wt[n * 128 + kc * 8];
        int b = 16384 + ((n * 256 + kc * 16) ^ ((n & 7) << 4));
        *(uint4*)&lds[b] = v;
    }
    __syncthreads();

    int w = tid >> 6, lane = tid & 63;
    int g = lane >> 4, l15 = lane & 15;
    int lrow = w * 16 + l15;

    short8 a[4];
#pragma unroll
    for (int s = 0; s < 4; ++s)
        a[s] = *(const short8*)&lds[(lrow * 256 + s * 64 + g * 16) ^ ((lrow & 7) << 4)];

    f32x4 acc[8];
#pragma unroll
    for (int f = 0; f < 8; ++f) acc[f] = (f32x4){0.f, 0.f, 0.f, 0.f};

    // ---- pass 1: emb ----
#pragma unroll
    for (int f = 0; f < 8; ++f) {
        int n = f * 16 + l15;
        int nsw = (n & 7) << 4;
#pragma unroll
        for (int s = 0; s < 4; ++s) {
            short8 b = *(const short8*)&lds[16384 + ((n * 256 + s * 64 + g * 16) ^ nsw)];
            acc[f] = __builtin_amdgcn_mfma_f32_16x16x32_bf16(a[s], b, acc[f], 0, 0, 0);
        }
    }
#pragma unroll
    for (int f = 0; f < 8; ++f) {
        int col = f * 16 + l15;
#pragma unroll
        for (int reg = 0; reg < 4; ++reg) {
            int grow = m0 + w * 16 + g * 4 + reg;
            if (grow < M) EmbBf[(size_t)grow * 128 + col] = f2bf(acc[f][reg]);
        }
    }
    // fused h_l/h_r epilogue
    {
        float alv[8], arv[8];
#pragma unroll
        for (int f = 0; f < 8; ++f) {
            alv[f] = a_l[f * 16 + l15];
            arv[f] = a_r[f * 16 + l15];
        }
#pragma unroll
        for (int reg = 0; reg < 4; ++reg) {
            float4 hl4, hr4;
#pragma unroll
            for (int hh = 0; hh < 4; ++hh) {
                float pl = alv[2 * hh] * acc[2 * hh][reg] + alv[2 * hh + 1] * acc[2 * hh + 1][reg];
                float pr = arv[2 * hh] * acc[2 * hh][reg] + arv[2 * hh + 1] * acc[2 * hh + 1][reg];
#pragma unroll
                for (int off = 8; off >= 1; off >>= 1) {
                    pl += __shfl_xor(pl, off);
                    pr += __shfl_xor(pr, off);
                }
                (&hl4.x)[hh] = pl;
                (&hr4.x)[hh] = pr;
            }
            int grow = m0 + w * 16 + g * 4 + reg;
            if (l15 == 0 && grow < M) {
                *(float4*)&h_l[(size_t)grow * 4] = hl4;
                *(float4*)&h_r[(size_t)grow * 4] = hr4;
            }
        }
    }

    // ---- pass 2: res ----
    __syncthreads();                            // all B reads done
#pragma unroll
    for (int i = 0; i < 8; ++i) {
        int c = tid + 256 * i;
        int n = c >> 4, kc = c & 15;
        uint4 v = *(const uint4*)&Rwt[n * 128 + kc * 8];
        int b = 16384 + ((n * 256 + kc * 16) ^ ((n & 7) << 4));
        *(uint4*)&lds[b] = v;
    }
    __syncthreads();

#pragma unroll
    for (int f = 0; f < 8; ++f) acc[f] = (f32x4){0.f, 0.f, 0.f, 0.f};
#pragma unroll
    for (int f = 0; f < 8; ++f) {
        int n = f * 16 + l15;
        int nsw = (n & 7) << 4;
#pragma unroll
        for (int s = 0; s < 4; ++s) {
            short8 b = *(const short8*)&lds[16384 + ((n * 256 + s * 64 + g * 16) ^ nsw)];
            acc[f] = __builtin_amdgcn_mfma_f32_16x16x32_bf16(a[s], b, acc[f], 0, 0, 0);
        }
    }
#pragma unroll
    for (int f = 0; f < 8; ++f) {
        int col = f * 16 + l15;
        float bias = Rb[col];
#pragma unroll
        for (int reg = 0; reg < 4; ++reg) {
            int grow = m0 + w * 16 + g * 4 + reg;
            if (grow < M) ResBf[(size_t)grow * 128 + col] = f2bf(acc[f][reg] + bias);
        }
    }
}

// ---------------------------------------------------------------------------
__global__ void k_hist(const int* __restrict__ col, int* __restrict__ cnt, int E) {
    int i = blockIdx.x * blockDim.x + threadIdx.x;
    if (i < E) atomicAdd(&cnt[col[i]], 1);
}

__global__ void k_scan1(const int* __restrict__ cnt, int* __restrict__ starts,
                        int* __restrict__ bsum, int N)
{
    __shared__ int sh[256];
    int t = threadIdx.x, n = blockIdx.x * 256 + t;
    int v = (n < N) ? cnt[n] : 0;
    sh[t] = v; __syncthreads();
    for (int off = 1; off < 256; off <<= 1) {
        int y = (t >= off) ? sh[t - off] : 0;
        __syncthreads();
        sh[t] += y;
        __syncthreads();
    }
    if (n < N) starts[n] = sh[t] - v;
    if (t == 255) bsum[blockIdx.x] = sh[255];
}

__global__ void k_scan2(const int* __restrict__ bsum, int* __restrict__ boff, int nb)
{
    __shared__ int sh[256];
    int t = threadIdx.x;
    int v = (t < nb) ? bsum[t] : 0;
    sh[t] = v; __syncthreads();
    for (int off = 1; off < 256; off <<= 1) {
        int y = (t >= off) ? sh[t - off] : 0;
        __syncthreads();
        sh[t] += y;
        __syncthreads();
    }
    if (t < nb) boff[t] = sh[t] - v;
}

__global__ void k_scan3(int* __restrict__ starts, const int* __restrict__ boff,
                        int* __restrict__ cursor, int N, int E)
{
    int t = threadIdx.x, n = blockIdx.x * 256 + t;
    if (n < N) {
        int st = starts[n] + boff[blockIdx.x];
        starts[n] = st;
        cursor[n] = st;
    }
    if (n == 0) starts[N] = E;
}

// ---------------------------------------------------------------------------
// Fill CSR payload: srcrow[pos] = row, scl[pos] = h_l[row] + h_e_t[etype].
__global__ void k_fill(const int* __restrict__ row, const int* __restrict__ col,
                       const int* __restrict__ etype, int* __restrict__ cursor,
                       const float* __restrict__ h_l, const float* __restrict__ h_e_t,
                       int* __restrict__ srcrow, float4* __restrict__ scl, int E)
{
    int i = blockIdx.x * blockDim.x + threadIdx.x;
    if (i < E) {
        int c = col[i];
        int pos = atomicAdd(&cursor[c], 1);
        int r = row[i];
        float4 hl = *(const float4*)&h_l[(size_t)r * 4];
        float4 he = *(const float4*)&h_e_t[(size_t)etype[i] * 4];
        srcrow[pos] = r;
        scl[pos] = make_float4(hl.x + he.x, hl.y + he.y, hl.z + he.z, hl.w + he.w);
    }
}

// ---------------------------------------------------------------------------
// One wave per destination node.  Fast path (deg<=64): softmax in registers,
// then normalized alpha + emb byte-offset parked in per-wave LDS (SoA,
// conflict-free), gather loop = 2 ds_read + 1 saddr global load + 2 FMA/edge.
// LDS per wave: offr[64] @0 (256B), alpha_h[64] @ 256+h*260  -> 1536B slice.
__global__ __launch_bounds__(256) void k_aggregate(
    const int* __restrict__ srcrow, const float4* __restrict__ scl,
    const int* __restrict__ starts, const float* __restrict__ h_r,
    const unsigned short* __restrict__ embBf,
    const unsigned short* __restrict__ resBf, float* __restrict__ out, int N)
{
    __shared__ char shalpha[4 * 1536];
    int n = (blockIdx.x * blockDim.x + threadIdx.x) >> 6;
    if (n >= N) return;
    int lane = threadIdx.x & 63;
    char* wb = &shalpha[(threadIdx.x >> 6) * 1536];
    int st0 = starts[n];
    int deg = starts[n + 1] - st0;
    float4 hrv = *(const float4*)&h_r[(size_t)n * 4];
    int myh = lane >> 4;
    float ax = 0.f, ay = 0.f;
    const char* embByte = (const char*)embBf;

    if (deg <= 64) {
        int r = 0;
        float sc0 = -INFINITY, sc1 = -INFINITY, sc2 = -INFINITY, sc3 = -INFINITY;
        bool act = lane < deg;
        if (act) {
            r = srcrow[st0 + lane];
            float4 s = scl[st0 + lane];
            sc0 = s.x + hrv.x; sc0 = sc0 > 0.f ? sc0 : NEG_SLOPE * sc0;
            sc1 = s.y + hrv.y; sc1 = sc1 > 0.f ? sc1 : NEG_SLOPE * sc1;
            sc2 = s.z + hrv.z; sc2 = sc2 > 0.f ? sc2 : NEG_SLOPE * sc2;
            sc3 = s.w + hrv.w; sc3 = sc3 > 0.f ? sc3 : NEG_SLOPE * sc3;
        }
        float m0 = sc0, m1 = sc1, m2 = sc2, m3 = sc3;
        if (deg > 16) {
#pragma unroll
            for (int off = 32; off >= 16; off >>= 1) {
                m0 = fmaxf(m0, __shfl_xor(m0, off));
                m1 = fmaxf(m1, __shfl_xor(m1, off));
                m2 = fmaxf(m2, __shfl_xor(m2, off));
                m3 = fmaxf(m3, __shfl_xor(m3, off));
            }
        }
#pragma unroll
        for (int off = 8; off >= 1; off >>= 1) {
            m0 = fmaxf(m0, __shfl_xor(m0, off));
            m1 = fmaxf(m1, __shfl_xor(m1, off));
            m2 = fmaxf(m2, __shfl_xor(m2, off));
            m3 = fmaxf(m3, __shfl_xor(m3, off));
        }
        float p0 = act ? __expf(sc0 - m0) : 0.f;
        float p1 = act ? __expf(sc1 - m1) : 0.f;
        float p2 = act ? __expf(sc2 - m2) : 0.f;
        float p3 = act ? __expf(sc3 - m3) : 0.f;
        float d0 = p0, d1 = p1, d2 = p2, d3 = p3;
        if (deg > 16) {
#pragma unroll
            for (int off = 32; off >= 16; off >>= 1) {
                d0 += __shfl_xor(d0, off); d1 += __shfl_xor(d1, off);
                d2 += __shfl_xor(d2, off); d3 += __shfl_xor(d3, off);
            }
        }
#pragma unroll
        for (int off = 8; off >= 1; off >>= 1) {
            d0 += __shfl_xor(d0, off); d1 += __shfl_xor(d1, off);
            d2 += __shfl_xor(d2, off); d3 += __shfl_xor(d3, off);
        }
        if (act) {
            *(int*)(wb + lane * 4) = r << 8;                 // emb byte offset
            *(float*)(wb + 256 + 0 * 260 + lane * 4) = p0 / d0;
            *(float*)(wb + 256 + 1 * 260 + lane * 4) = p1 / d1;
            *(float*)(wb + 256 + 2 * 260 + lane * 4) = p2 / d2;
            *(float*)(wb + 256 + 3 * 260 + lane * 4) = p3 / d3;
        }
        const char* ab = wb + 256 + myh * 260;
        int q = 0;
        for (; q + 8 <= deg; q += 8) {
            int ro[8]; float aq[8];
#pragma unroll
            for (int u = 0; u < 8; ++u) ro[u] = *(const int*)(wb + (q + u) * 4);
#pragma unroll
            for (int u = 0; u < 8; ++u) aq[u] = *(const float*)(ab + (q + u) * 4);
            unsigned int ev[8];
#pragma unroll
            for (int u = 0; u < 8; ++u)
                ev[u] = *(const unsigned int*)(embByte + (size_t)(unsigned)(ro[u] + lane * 4));
#pragma unroll
            for (int u = 0; u < 8; ++u) {
                ax += aq[u] * bf2f((unsigned short)(ev[u] & 0xffffu));
                ay += aq[u] * bf2f((unsigned short)(ev[u] >> 16));
            }
        }
        for (; q < deg; ++q) {
            int ro = *(const int*)(wb + q * 4);
            float aq = *(const float*)(ab + q * 4);
            unsigned int ev = *(const unsigned int*)(embByte + (size_t)(unsigned)(ro + lane * 4));
            ax += aq * bf2f((unsigned short)(ev & 0xffffu));
            ay += aq * bf2f((unsigned short)(ev >> 16));
        }
    } else {
        // ---- general chunked path (rare): shuffle-broadcast version ----
        float m0 = -INFINITY, m1 = -INFINITY, m2 = -INFINITY, m3 = -INFINITY;
        for (int base = 0; base < deg; base += 64) {
            int el = base + lane;
            if (el < deg) {
                float4 s = scl[st0 + el];
                float sc0 = s.x + hrv.x; sc0 = sc0 > 0.f ? sc0 : NEG_SLOPE * sc0;
                float sc1 = s.y + hrv.y; sc1 = sc1 > 0.f ? sc1 : NEG_SLOPE * sc1;
                float sc2 = s.z + hrv.z; sc2 = sc2 > 0.f ? sc2 : NEG_SLOPE * sc2;
                float sc3 = s.w + hrv.w; sc3 = sc3 > 0.f ? sc3 : NEG_SLOPE * sc3;
                m0 = fmaxf(m0, sc0); m1 = fmaxf(m1, sc1);
                m2 = fmaxf(m2, sc2); m3 = fmaxf(m3, sc3);
            }
        }
#pragma unroll
        for (int off = 32; off >= 1; off >>= 1) {
            m0 = fmaxf(m0, __shfl_xor(m0, off));
            m1 = fmaxf(m1, __shfl_xor(m1, off));
            m2 = fmaxf(m2, __shfl_xor(m2, off));
            m3 = fmaxf(m3, __shfl_xor(m3, off));
        }
        float d0 = 0.f, d1 = 0.f, d2 = 0.f, d3 = 0.f;
        for (int base = 0; base < deg; base += 64) {
            int el = base + lane;
            if (el < deg) {
                float4 s = scl[st0 + el];
                float sc0 = s.x + hrv.x; sc0 = sc0 > 0.f ? sc0 : NEG_SLOPE * sc0;
                float sc1 = s.y + hrv.y; sc1 = sc1 > 0.f ? sc1 : NEG_SLOPE * sc1;
                float sc2 = s.z + hrv.z; sc2 = sc2 > 0.f ? sc2 : NEG_SLOPE * sc2;
                float sc3 = s.w + hrv.w; sc3 = sc3 > 0.f ? sc3 : NEG_SLOPE * sc3;
                d0 += __expf(sc0 - m0); d1 += __expf(sc1 - m1);
                d2 += __expf(sc2 - m2); d3 += __expf(sc3 - m3);
            }
        }
#pragma unroll
        for (int off = 32; off >= 1; off >>= 1) {
            d0 += __shfl_xor(d0, off); d1 += __shfl_xor(d1, off);
            d2 += __shfl_xor(d2, off); d3 += __shfl_xor(d3, off);
        }
        float den = myh == 0 ? d0 : myh == 1 ? d1 : myh == 2 ? d2 : d3;
        float inv = 1.f / den;
        for (int base = 0; base < deg; base += 64) {
            int el = base + lane;
            float p0 = 0.f, p1 = 0.f, p2 = 0.f, p3 = 0.f;
            int r = 0;
            if (el < deg) {
                r = srcrow[st0 + el];
                float4 s = scl[st0 + el];
                float sc0 = s.x + hrv.x; sc0 = sc0 > 0.f ? sc0 : NEG_SLOPE * sc0;
                float sc1 = s.y + hrv.y; sc1 = sc1 > 0.f ? sc1 : NEG_SLOPE * sc1;
                float sc2 = s.z + hrv.z; sc2 = sc2 > 0.f ? sc2 : NEG_SLOPE * sc2;
                float sc3 = s.w + hrv.w; sc3 = sc3 > 0.f ? sc3 : NEG_SLOPE * sc3;
                p0 = __expf(sc0 - m0); p1 = __expf(sc1 - m1);
                p2 = __expf(sc2 - m2); p3 = __expf(sc3 - m3);
            }
            int cmax = (deg - base < 64) ? (deg - base) : 64;
            for (int qq = 0; qq < cmax; ++qq) {
                int rq = __shfl(r, qq);
                float a0 = __shfl(p0, qq), a1 = __shfl(p1, qq);
                float a2 = __shfl(p2, qq), a3 = __shfl(p3, qq);
                float aq = myh == 0 ? a0 : myh == 1 ? a1 : myh == 2 ? a2 : a3;
                unsigned int ev = *(const unsigned int*)&embBf[(size_t)rq * 128 + lane * 2];
                ax += aq * bf2f((unsigned short)(ev & 0xffffu));
                ay += aq * bf2f((unsigned short)(ev >> 16));
            }
        }
        ax *= inv; ay *= inv;
    }

    // epilogue: transpose to d-major, + residual (bf16), ELU
    int j0 = lane * 2;
    int h0 = j0 >> 5, dd0 = j0 & 31;
    size_t ob = (size_t)n * 128;
    float o0 = ax + bf2f(resBf[ob + dd0 * 4 + h0]);
    float o1 = ay + bf2f(resBf[ob + (dd0 + 1) * 4 + h0]);
    out[ob + dd0 * 4 + h0] = o0 > 0.f ? o0 : expm1f(o0);
    out[ob + (dd0 + 1) * 4 + h0] = o1 > 0.f ? o1 : expm1f(o1);
}

// ---------------------------------------------------------------------------
extern "C" void kernel_launch(void* const* d_in, const int* in_sizes, int n_in,
                              void* d_out, int out_size, void* d_ws, size_t ws_size,
                              hipStream_t stream)
{
    const float* h        = (const float*)d_in[0];
    const float* W        = (const float*)d_in[1];
    const float* edge_emb = (const float*)d_in[2];
    const float* W_r      = (const float*)d_in[3];
    const float* a_l      = (const float*)d_in[4];
    const float* a_r      = (const float*)d_in[5];
    const float* a_e      = (const float*)d_in[6];
    const float* res_w    = (const float*)d_in[7];
    const float* res_b    = (const float*)d_in[8];
    const int*   row      = (const int*)d_in[9];
    const int*   col      = (const int*)d_in[10];
    const int*   etype    = (const int*)d_in[11];
    float* out = (float*)d_out;

    int N = in_sizes[0] / IN_DIM;
    int E = in_sizes[9];
    int T = in_sizes[2] / EDIM;

    char* ws = (char*)d_ws;
    size_t off = 0;
    auto alloc = [&](size_t bytes) -> char* {
        char* p = ws + off;
        off = (off + bytes + 255) & ~(size_t)255;
        return p;
    };
    unsigned short* embBf = (unsigned short*)alloc((size_t)N * 128 * 2);
    unsigned short* resBf = (unsigned short*)alloc((size_t)N * 128 * 2);
    unsigned short* Wt    = (unsigned short*)alloc((size_t)128 * 128 * 2);
    unsigned short* Rwt   = (unsigned short*)alloc((size_t)128 * 128 * 2);
    float* h_l   = (float*)alloc((size_t)N * 4 * 4);
    float* h_r   = (float*)alloc((size_t)N * 4 * 4);
    float* h_e_t = (float*)alloc((size_t)T * 4 * 4);
    int* starts  = (int*)alloc((size_t)(N + 1) * 4);
    int* cursor  = (int*)alloc((size_t)N * 4);
    int* bsum    = (int*)alloc(256 * 4);
    int* boff    = (int*)alloc(256 * 4);
    int* srcrow  = (int*)alloc((size_t)E * 4);
    float4* scl  = (float4*)alloc((size_t)E * 16);

    int nb  = (N + 255) / 256;
    int neb = (E + 255) / 256;

    hipLaunchKernelGGL(k_edge_type, dim3(T), dim3(128), 0, stream,
                       edge_emb, W_r, a_e, h_e_t);
    hipLaunchKernelGGL(k_prep_w, dim3(64), dim3(256), 0, stream,
                       W, res_w, Wt, Rwt, cursor, N);
    hipLaunchKernelGGL(k_gemm_mfma, dim3((N + 63) / 64), dim3(256), 0, stream,
                       h, Wt, Rwt, res_b, a_l, a_r, embBf, resBf, h_l, h_r, N);
    hipLaunchKernelGGL(k_hist, dim3(neb), dim3(256), 0, stream, col, cursor, E);
    hipLaunchKernelGGL(k_scan1, dim3(nb), dim3(256), 0, stream, cursor, starts, bsum, N);
    hipLaunchKernelGGL(k_scan2, dim3(1), dim3(256), 0, stream, bsum, boff, nb);
    hipLaunchKernelGGL(k_scan3, dim3(nb), dim3(256), 0, stream, starts, boff, cursor, N, E);
    hipLaunchKernelGGL(k_fill, dim3(neb), dim3(256), 0, stream,
                       row, col, etype, cursor, h_l, h_e_t, srcrow, scl, E);
    hipLaunchKernelGGL(k_aggregate, dim3((N + 3) / 4), dim3(256), 0, stream,
                       srcrow, scl, starts, h_r, embBf, resBf, out, N);
}